// Round 2
// baseline (347.016 us; speedup 1.0000x reference)
//
#include <hip/hip_runtime.h>

#define HID 256
#define EF  64
#define KIN 320      // HID + EF
#define NC  4096
#define NE  65536
#define BSZ 4
#define EPSV 1e-5f
#define PSTR 512     // P row stride (floats): [x@mW1a | x@uW1a]

typedef unsigned short ushort_t;
typedef __attribute__((ext_vector_type(8))) short s16x8;
typedef __attribute__((ext_vector_type(16))) float f32x16;

// LDS strides in ushort elements
#define XPAD 328     // edge X tile row (fallback): 656 B
#define EPAD 72      // edge-attr tile row: 144 B
#define HPAD 264     // hidden tile row: 528 B
#define UPAD 520     // node LDS pool row: 1040 B
#define HSF  260     // node h (fp32) stride

// round-to-nearest-even fp32 -> bf16 (as ushort bits)
__device__ __forceinline__ ushort_t bf16_rne(float f) {
    unsigned u = __float_as_uint(f);
    return (ushort_t)((u + 0x7fffu + ((u >> 16) & 1u)) >> 16);
}
__device__ __forceinline__ float bf16_to_f(ushort_t u) {
    return __uint_as_float(((unsigned)u) << 16);
}
// truncating hi/lo split (pair sums to ~fp32 precision) — for weights (B operand)
__device__ __forceinline__ void split_bf16(float v, ushort_t& h, ushort_t& l) {
    unsigned u = __float_as_uint(v);
    h = (ushort_t)(u >> 16);
    float hf = __uint_as_float(u & 0xffff0000u);
    l = (ushort_t)(__float_as_uint(v - hf) >> 16);
}

// Pack weights into 32x32x16 MFMA B-fragment order, hi/lo bf16.
// frag idx = (t*8 + nt)*64 + lane; elem j: W[t*16 + (lane>>5)*8 + j][nt*32 + (lane&31)]
__device__ __forceinline__ void pack_one(const float* W, int idx,
                                         ushort_t* hi, ushort_t* lo) {
    int l = idx & 63;
    int tn = idx >> 6;
    int nt = tn & 7, t = tn >> 3;
    int k0 = t * 16 + (l >> 5) * 8;
    int col = nt * 32 + (l & 31);
    #pragma unroll
    for (int j = 0; j < 8; ++j) {
        float v = W[(size_t)(k0 + j) * 256 + col];
        ushort_t h, lw;
        split_bf16(v, h, lw);
        hi[(size_t)idx * 8 + j] = h;
        lo[(size_t)idx * 8 + j] = lw;
    }
}

#define FR1 10240    // (320/16)*8*64
#define FR2 8192     // (256/16)*8*64
#define FR3 16384    // (512/16)*8*64
#define PACKB 168    // ceil((FR1+2*FR2+FR3)/256) = 43008/256
#define ZEROB 256    // blocks for the zero path

// blocks [0,PACKB): pack weights; blocks [PACKB, PACKB+ZEROB): zero aggbf+counts
__global__ __launch_bounds__(256)
void prep_kernel(const float* __restrict__ mW1, const float* __restrict__ mW2,
                 const float* __restrict__ uW1, const float* __restrict__ uW2,
                 ushort_t* __restrict__ w1hi, ushort_t* __restrict__ w1lo,
                 ushort_t* __restrict__ w2hi, ushort_t* __restrict__ w2lo,
                 ushort_t* __restrict__ u1hi, ushort_t* __restrict__ u1lo,
                 ushort_t* __restrict__ u2hi, ushort_t* __restrict__ u2lo,
                 float4* __restrict__ zp, int n4) {
    if (blockIdx.x >= PACKB) {
        int i = (blockIdx.x - PACKB) * 256 + threadIdx.x;
        int stride = ZEROB * 256;
        float4 z = make_float4(0.f, 0.f, 0.f, 0.f);
        for (; i < n4; i += stride) zp[i] = z;
        return;
    }
    int idx = blockIdx.x * 256 + threadIdx.x;
    if (idx < FR1) { pack_one(mW1, idx, w1hi, w1lo); return; }
    idx -= FR1;
    if (idx < FR2) { pack_one(mW2, idx, w2hi, w2lo); return; }
    idx -= FR2;
    if (idx < FR3) { pack_one(uW1, idx, u1hi, u1lo); return; }
    idx -= FR3;
    if (idx < FR2) { pack_one(uW2, idx, u2hi, u2lo); return; }
}

// ======================= P path =======================
// P = cell_x @ [mW1[:256,:] | uW1[:256,:]]  -> [B*NC, 512] fp32
// 32 rows/block, 512 threads = 8 waves; wave wv owns n-cols wv*32 (both halves)
__global__ __launch_bounds__(512, 6)
void pre_kernel(const float* __restrict__ cell_x,
                const ushort_t* __restrict__ w1hi, const ushort_t* __restrict__ w1lo,
                const ushort_t* __restrict__ u1hi, const ushort_t* __restrict__ u1lo,
                float* __restrict__ P) {
    __shared__ ushort_t Us[32 * HPAD];   // 16,896 B

    const int tid = threadIdx.x;
    const size_t r0 = (size_t)blockIdx.x * 32;     // global row in [0, B*NC)
    const int wv = tid >> 6, ln = tid & 63;
    const int m32 = ln & 31, half = ln >> 5;
    const int col = wv * 32 + m32;

    // hoisted B prefetch (t=0, both weights, hi/lo)
    const ushort_t* wph = w1hi + ((size_t)wv * 64 + ln) * 8;
    const ushort_t* wpl = w1lo + ((size_t)wv * 64 + ln) * 8;
    const ushort_t* uph = u1hi + ((size_t)wv * 64 + ln) * 8;
    const ushort_t* upl = u1lo + ((size_t)wv * 64 + ln) * 8;
    s16x8 wh = *(const s16x8*)wph, wl = *(const s16x8*)wpl;
    s16x8 uh = *(const s16x8*)uph, ul = *(const s16x8*)upl;

    // stage cell_x rows as RNE bf16
    {
        const int row = tid >> 4, c8 = tid & 15;
        const float4* crow = (const float4*)(cell_x + (r0 + row) * HID);
        #pragma unroll
        for (int i = 0; i < 4; ++i) {
            int c = c8 + i * 16;
            float4 v = crow[c];
            *(ushort4*)&Us[row * HPAD + c * 4] =
                make_ushort4(bf16_rne(v.x), bf16_rne(v.y), bf16_rne(v.z), bf16_rne(v.w));
        }
    }
    __syncthreads();

    f32x16 aw, au;
    #pragma unroll
    for (int r = 0; r < 16; ++r) { aw[r] = 0.f; au[r] = 0.f; }

    #pragma unroll 2
    for (int t = 0; t < 16; ++t) {
        int tn = (t + 1 < 16) ? t + 1 : 15;
        s16x8 whn = *(const s16x8*)(wph + (size_t)tn * 4096);
        s16x8 wln = *(const s16x8*)(wpl + (size_t)tn * 4096);
        s16x8 uhn = *(const s16x8*)(uph + (size_t)tn * 4096);
        s16x8 uln = *(const s16x8*)(upl + (size_t)tn * 4096);
        s16x8 a = *(const s16x8*)&Us[m32 * HPAD + t * 16 + half * 8];
        aw = __builtin_amdgcn_mfma_f32_32x32x16_bf16(a, wh, aw, 0, 0, 0);
        aw = __builtin_amdgcn_mfma_f32_32x32x16_bf16(a, wl, aw, 0, 0, 0);
        au = __builtin_amdgcn_mfma_f32_32x32x16_bf16(a, uh, au, 0, 0, 0);
        au = __builtin_amdgcn_mfma_f32_32x32x16_bf16(a, ul, au, 0, 0, 0);
        wh = whn; wl = wln; uh = uhn; ul = uln;
    }

    #pragma unroll
    for (int r = 0; r < 16; ++r) {
        int row = (r & 3) + 8 * (r >> 2) + 4 * half;
        float* prow = P + (r0 + row) * PSTR;
        prow[col]       = aw[r];
        prow[256 + col] = au[r];
    }
}

// 64 edges/block, 512 threads = 8 waves; wave wv owns n-tile wv, 2 m-tiles
__global__ __launch_bounds__(512, 6)
void edge_kernel(const float* __restrict__ Pmat,
                 const int*   __restrict__ eidx,
                 const float* __restrict__ eattr,
                 const ushort_t* __restrict__ w1hi, const ushort_t* __restrict__ w1lo,
                 const float* __restrict__ b1,
                 const ushort_t* __restrict__ w2hi, const ushort_t* __restrict__ w2lo,
                 const float* __restrict__ b2,
                 ushort_t* __restrict__ aggbf, float* __restrict__ counts) {
    __shared__ ushort_t Xs[64 * HPAD];   // 33,792 B; staging uses EPAD sub-layout
    __shared__ int s_src[64], s_dst[64];

    const int tid = threadIdx.x;
    const int b   = blockIdx.x >> 10;            // 1024 blocks per batch
    const int e0  = (blockIdx.x & 1023) * 64;
    const int wv = tid >> 6, ln = tid & 63;
    const int m32 = ln & 31, half = ln >> 5;
    const int col = wv * 32 + m32;

    // ---- hoisted W1b (eattr-part, packed t=16..19) B-prefetch ----
    const ushort_t* b1ph = w1hi + ((size_t)(16 * 8 + wv) * 64 + ln) * 8;
    const ushort_t* b1pl = w1lo + ((size_t)(16 * 8 + wv) * 64 + ln) * 8;
    s16x8 bh0 = *(const s16x8*)b1ph;
    s16x8 bl0 = *(const s16x8*)b1pl;
    s16x8 bh1 = *(const s16x8*)(b1ph + 4096);
    s16x8 bl1 = *(const s16x8*)(b1pl + 4096);

    if (tid < 64) {
        int2 v = ((const int2*)eidx)[(size_t)b * NE + e0 + tid];
        int dv = min(max(v.y, 0), NC - 1);
        s_src[tid] = min(max(v.x, 0), NC - 1);
        s_dst[tid] = dv;
        atomicAdd(&counts[b * NC + dv], 1.0f);   // fused degree count
    }
    __syncthreads();

    // ---- stage eattr (64x64) as RNE bf16 ----
    {
        const int row = tid >> 3, c8 = tid & 7;
        const float4* arow = (const float4*)(eattr + ((size_t)b * NE + e0 + row) * EF);
        #pragma unroll
        for (int i = 0; i < 2; ++i) {
            int c = c8 + i * 8;                  // float4 index 0..15
            float4 v = arow[c];
            *(ushort4*)&Xs[row * EPAD + c * 4] =
                make_ushort4(bf16_rne(v.x), bf16_rne(v.y), bf16_rne(v.z), bf16_rne(v.w));
        }
    }
    __syncthreads();

    // ---- GEMM1': acc = eattr @ W1b + b1, K=64, 4 k-steps ----
    f32x16 A0, A1;
    {
        float bias = b1[col];
        #pragma unroll
        for (int r = 0; r < 16; ++r) { A0[r] = bias; A1[r] = bias; }
    }
    #pragma unroll
    for (int t = 0; t < 4; t += 2) {
        s16x8 nh = *(const s16x8*)(b1ph + (size_t)min(t + 2, 3) * 4096);
        s16x8 nl = *(const s16x8*)(b1pl + (size_t)min(t + 2, 3) * 4096);
        int ao = m32 * EPAD + t * 16 + half * 8;
        s16x8 a0 = *(const s16x8*)&Xs[ao];
        s16x8 a1 = *(const s16x8*)&Xs[ao + 32 * EPAD];
        A0 = __builtin_amdgcn_mfma_f32_32x32x16_bf16(a0, bh0, A0, 0, 0, 0);
        A0 = __builtin_amdgcn_mfma_f32_32x32x16_bf16(a0, bl0, A0, 0, 0, 0);
        A1 = __builtin_amdgcn_mfma_f32_32x32x16_bf16(a1, bh0, A1, 0, 0, 0);
        A1 = __builtin_amdgcn_mfma_f32_32x32x16_bf16(a1, bl0, A1, 0, 0, 0);
        bh0 = nh; bl0 = nl;
        nh = *(const s16x8*)(b1ph + (size_t)min(t + 3, 3) * 4096);
        nl = *(const s16x8*)(b1pl + (size_t)min(t + 3, 3) * 4096);
        ao = m32 * EPAD + (t + 1) * 16 + half * 8;
        a0 = *(const s16x8*)&Xs[ao];
        a1 = *(const s16x8*)&Xs[ao + 32 * EPAD];
        A0 = __builtin_amdgcn_mfma_f32_32x32x16_bf16(a0, bh1, A0, 0, 0, 0);
        A0 = __builtin_amdgcn_mfma_f32_32x32x16_bf16(a0, bl1, A0, 0, 0, 0);
        A1 = __builtin_amdgcn_mfma_f32_32x32x16_bf16(a1, bh1, A1, 0, 0, 0);
        A1 = __builtin_amdgcn_mfma_f32_32x32x16_bf16(a1, bl1, A1, 0, 0, 0);
        bh1 = nh; bl1 = nl;
    }

    // ---- add gathered P[src] (fp32, coalesced in col; rows L2-resident) ----
    {
        const float* pb = Pmat + (size_t)b * NC * PSTR + col;
        #pragma unroll
        for (int r = 0; r < 16; ++r) {
            int rw = (r & 3) + 8 * (r >> 2) + 4 * half;
            A0[r] += pb[(size_t)s_src[rw] * PSTR];
            A1[r] += pb[(size_t)s_src[rw + 32] * PSTR];
        }
    }

    // ---- hoisted W2 B-prefetch (covers cold latency under repack + barrier) ----
    const ushort_t* b2ph = w2hi + ((size_t)wv * 64 + ln) * 8;
    const ushort_t* b2pl = w2lo + ((size_t)wv * 64 + ln) * 8;
    bh0 = *(const s16x8*)b2ph;
    bl0 = *(const s16x8*)b2pl;
    bh1 = *(const s16x8*)(b2ph + 4096);
    bl1 = *(const s16x8*)(b2pl + 4096);

    __syncthreads();   // all eattr reads done; reuse LDS for H

    // ---- relu + RNE bf16 + store hidden (rows = edges) ----
    #pragma unroll
    for (int r = 0; r < 16; ++r) {
        int row = (r & 3) + 8 * (r >> 2) + 4 * half;
        Xs[row * HPAD + col]        = bf16_rne(fmaxf(A0[r], 0.f));
        Xs[(row + 32) * HPAD + col] = bf16_rne(fmaxf(A1[r], 0.f));
    }
    __syncthreads();

    // ---- GEMM2: msg = hidden @ W2 + b2, K=256, 16 k-steps ----
    f32x16 C0, C1;
    {
        float bias = b2[col];
        #pragma unroll
        for (int r = 0; r < 16; ++r) { C0[r] = bias; C1[r] = bias; }
    }
    for (int t = 0; t < 16; t += 2) {
        s16x8 nh = *(const s16x8*)(b2ph + (size_t)min(t + 2, 15) * 4096);
        s16x8 nl = *(const s16x8*)(b2pl + (size_t)min(t + 2, 15) * 4096);
        int ao = m32 * HPAD + t * 16 + half * 8;
        s16x8 a0 = *(const s16x8*)&Xs[ao];
        s16x8 a1 = *(const s16x8*)&Xs[ao + 32 * HPAD];
        C0 = __builtin_amdgcn_mfma_f32_32x32x16_bf16(a0, bh0, C0, 0, 0, 0);
        C0 = __builtin_amdgcn_mfma_f32_32x32x16_bf16(a0, bl0, C0, 0, 0, 0);
        C1 = __builtin_amdgcn_mfma_f32_32x32x16_bf16(a1, bh0, C1, 0, 0, 0);
        C1 = __builtin_amdgcn_mfma_f32_32x32x16_bf16(a1, bl0, C1, 0, 0, 0);
        bh0 = nh; bl0 = nl;
        nh = *(const s16x8*)(b2ph + (size_t)min(t + 3, 15) * 4096);
        nl = *(const s16x8*)(b2pl + (size_t)min(t + 3, 15) * 4096);
        ao = m32 * HPAD + (t + 1) * 16 + half * 8;
        a0 = *(const s16x8*)&Xs[ao];
        a1 = *(const s16x8*)&Xs[ao + 32 * HPAD];
        C0 = __builtin_amdgcn_mfma_f32_32x32x16_bf16(a0, bh1, C0, 0, 0, 0);
        C0 = __builtin_amdgcn_mfma_f32_32x32x16_bf16(a0, bl1, C0, 0, 0, 0);
        C1 = __builtin_amdgcn_mfma_f32_32x32x16_bf16(a1, bh1, C1, 0, 0, 0);
        C1 = __builtin_amdgcn_mfma_f32_32x32x16_bf16(a1, bl1, C1, 0, 0, 0);
        bh1 = nh; bl1 = nl;
    }

    // ---- packed bf16 scatter-add into aggbf[b, dst, col&~1 .. +1] ----
    const int colbase = col & ~1;
    const bool evenl = (m32 & 1) == 0;
    #pragma unroll
    for (int r = 0; r < 16; ++r) {
        int row = (r & 3) + 8 * (r >> 2) + 4 * half;
        {
            float other = __shfl_xor(C0[r], 1, 64);
            float vlo = evenl ? C0[r] : other;
            float vhi = evenl ? other : C0[r];
            if (evenl == (r < 8)) {
                unsigned pk = ((unsigned)bf16_rne(vhi) << 16) | (unsigned)bf16_rne(vlo);
                ushort_t* addr = aggbf + ((size_t)b * NC + s_dst[row]) * HID + colbase;
                asm volatile("global_atomic_pk_add_bf16 %0, %1, off"
                             :: "v"(addr), "v"(pk) : "memory");
            }
        }
        {
            float other = __shfl_xor(C1[r], 1, 64);
            float vlo = evenl ? C1[r] : other;
            float vhi = evenl ? other : C1[r];
            if (evenl == (r < 8)) {
                unsigned pk = ((unsigned)bf16_rne(vhi) << 16) | (unsigned)bf16_rne(vlo);
                ushort_t* addr = aggbf + ((size_t)b * NC + s_dst[row + 32]) * HID + colbase;
                asm volatile("global_atomic_pk_add_bf16 %0, %1, off"
                             :: "v"(addr), "v"(pk) : "memory");
            }
        }
    }
}

// 32 nodes/block, 512 threads = 8 waves; wave wv owns n-tile wv, 1 m-tile
__global__ __launch_bounds__(512, 6)
void node_kernel(const float* __restrict__ cell_x,
                 const ushort_t* __restrict__ aggbf,
                 const float* __restrict__ counts,
                 const float* __restrict__ Pmat,
                 const ushort_t* __restrict__ u1hi, const ushort_t* __restrict__ u1lo,
                 const float* __restrict__ b1,
                 const ushort_t* __restrict__ u2hi, const ushort_t* __restrict__ u2lo,
                 const float* __restrict__ b2,
                 const float* __restrict__ gamma, const float* __restrict__ beta,
                 float* __restrict__ out) {
    __shared__ ushort_t Us[32 * UPAD];   // pool: agg/H bf16 (32*HPAD) + hs fp32 overlay
    __shared__ float s_inv[32];
    float* hs = (float*)Us;

    const int tid = threadIdx.x;
    const int b   = blockIdx.x >> 7;             // 128 blocks per batch
    const int r0  = (blockIdx.x & 127) * 32;
    const int wv = tid >> 6, ln = tid & 63;
    const int m32 = ln & 31, half = ln >> 5;
    const int col = wv * 32 + m32;

    // hoisted uW1b (agg-part, packed t=16..31) B-prefetch
    const ushort_t* b1ph = u1hi + ((size_t)(16 * 8 + wv) * 64 + ln) * 8;
    const ushort_t* b1pl = u1lo + ((size_t)(16 * 8 + wv) * 64 + ln) * 8;
    s16x8 bhi = *(const s16x8*)b1ph;
    s16x8 blo = *(const s16x8*)b1pl;

    if (tid < 32) {
        float c = counts[b * NC + r0 + tid];
        s_inv[tid] = 1.0f / fmaxf(c, 1.0f);
    }
    __syncthreads();

    // ---- stage agg/cnt as RNE bf16 (32 x 256) ----
    {
        const int row = tid >> 4, c8 = tid & 15;
        const ushort4* grow = (const ushort4*)(aggbf + ((size_t)b * NC + r0 + row) * HID);
        float inv = s_inv[row];
        #pragma unroll
        for (int i = 0; i < 4; ++i) {
            int c = c8 + i * 16;                 // 4-elem group index 0..63
            ushort4 g = grow[c];
            *(ushort4*)&Us[row * HPAD + c * 4] =
                make_ushort4(bf16_rne(bf16_to_f(g.x) * inv),
                             bf16_rne(bf16_to_f(g.y) * inv),
                             bf16_rne(bf16_to_f(g.z) * inv),
                             bf16_rne(bf16_to_f(g.w) * inv));
        }
    }
    __syncthreads();

    // ---- GEMM1': acc = agg @ uW1b + ub1, K=256, 16 k-steps ----
    f32x16 acc;
    {
        float bias = b1[col];
        #pragma unroll
        for (int r = 0; r < 16; ++r) acc[r] = bias;
    }
    #pragma unroll 2
    for (int t = 0; t < 16; ++t) {
        int tn1 = (t + 1 < 16) ? t + 1 : 15;
        s16x8 bhin = *(const s16x8*)(b1ph + (size_t)tn1 * 4096);
        s16x8 blon = *(const s16x8*)(b1pl + (size_t)tn1 * 4096);
        s16x8 a = *(const s16x8*)&Us[m32 * HPAD + t * 16 + half * 8];
        acc = __builtin_amdgcn_mfma_f32_32x32x16_bf16(a, bhi, acc, 0, 0, 0);
        acc = __builtin_amdgcn_mfma_f32_32x32x16_bf16(a, blo, acc, 0, 0, 0);
        bhi = bhin; blo = blon;
    }

    // ---- add P (cell_x @ uW1a half; contiguous rows, coalesced) ----
    {
        const float* pb = Pmat + ((size_t)b * NC + r0) * PSTR + 256 + col;
        #pragma unroll
        for (int r = 0; r < 16; ++r) {
            int row = (r & 3) + 8 * (r >> 2) + 4 * half;
            acc[r] += pb[(size_t)row * PSTR];
        }
    }

    // hoisted uW2 B-prefetch (before repack barrier)
    const ushort_t* b2ph = u2hi + ((size_t)wv * 64 + ln) * 8;
    const ushort_t* b2pl = u2lo + ((size_t)wv * 64 + ln) * 8;
    bhi = *(const s16x8*)b2ph;
    blo = *(const s16x8*)b2pl;

    __syncthreads();   // agg tile dead; reuse for H

    #pragma unroll
    for (int r = 0; r < 16; ++r) {
        int row = (r & 3) + 8 * (r >> 2) + 4 * half;
        Us[row * HPAD + col] = bf16_rne(fmaxf(acc[r], 0.f));
    }
    __syncthreads();

    // ---- GEMM2: o = hidden @ uW2 + ub2, K=256, 16 k-steps ----
    f32x16 c2;
    {
        float bias = b2[col];
        #pragma unroll
        for (int r = 0; r < 16; ++r) c2[r] = bias;
    }
    #pragma unroll 2
    for (int t = 0; t < 16; ++t) {
        int tn1 = (t + 1 < 16) ? t + 1 : 15;
        s16x8 bhin = *(const s16x8*)(b2ph + (size_t)tn1 * 4096);
        s16x8 blon = *(const s16x8*)(b2pl + (size_t)tn1 * 4096);
        s16x8 a = *(const s16x8*)&Us[m32 * HPAD + t * 16 + half * 8];
        c2 = __builtin_amdgcn_mfma_f32_32x32x16_bf16(a, bhi, c2, 0, 0, 0);
        c2 = __builtin_amdgcn_mfma_f32_32x32x16_bf16(a, blo, c2, 0, 0, 0);
        bhi = bhin; blo = blon;
    }
    __syncthreads();   // H dead; reuse pool for hs (fp32)

    // ---- residual: h = cell_x + o ----
    #pragma unroll
    for (int r = 0; r < 16; ++r) {
        int row = (r & 3) + 8 * (r >> 2) + 4 * half;
        float cx = cell_x[((size_t)b * NC + r0 + row) * HID + col];
        hs[row * HSF + col] = c2[r] + cx;
    }
    __syncthreads();

    // ---- LayerNorm per row: wave wv handles rows wv*4..+3 ----
    #pragma unroll
    for (int i = 0; i < 4; ++i) {
        int r = wv * 4 + i;
        float v[4];
        float s = 0.f, q = 0.f;
        #pragma unroll
        for (int j = 0; j < 4; ++j) {
            v[j] = hs[r * HSF + ln + 64 * j];
            s += v[j];
            q = fmaf(v[j], v[j], q);
        }
        #pragma unroll
        for (int off = 32; off > 0; off >>= 1) {
            s += __shfl_xor(s, off, 64);
            q += __shfl_xor(q, off, 64);
        }
        float mu = s * (1.0f / HID);
        float var = q * (1.0f / HID) - mu * mu;
        float rs = rsqrtf(var + EPSV);
        float* orow = out + ((size_t)b * NC + r0 + r) * HID;
        #pragma unroll
        for (int j = 0; j < 4; ++j) {
            int c = ln + 64 * j;
            orow[c] = (v[j] - mu) * rs * gamma[c] + beta[c];
        }
    }
}

// ======================= fallback path (round-0 baseline, ~9.4 MB ws) =======================
__global__ __launch_bounds__(512, 6)
void edge_kernel_fb(const float* __restrict__ cell_x,
                    const int*   __restrict__ eidx,
                    const float* __restrict__ eattr,
                    const ushort_t* __restrict__ w1hi, const ushort_t* __restrict__ w1lo,
                    const float* __restrict__ b1,
                    const ushort_t* __restrict__ w2hi, const ushort_t* __restrict__ w2lo,
                    const float* __restrict__ b2,
                    ushort_t* __restrict__ aggbf, float* __restrict__ counts) {
    __shared__ ushort_t Xs[64 * XPAD];   // 41,984 B; reused as H (64*HPAD*2 = 33,792 B)
    __shared__ int s_src[64], s_dst[64];

    const int tid = threadIdx.x;
    const int b   = blockIdx.x >> 10;
    const int e0  = (blockIdx.x & 1023) * 64;
    const int wv = tid >> 6, ln = tid & 63;
    const int m32 = ln & 31, half = ln >> 5;
    const int col = wv * 32 + m32;

    const ushort_t* b1ph = w1hi + ((size_t)wv * 64 + ln) * 8;
    const ushort_t* b1pl = w1lo + ((size_t)wv * 64 + ln) * 8;
    s16x8 bh0 = *(const s16x8*)b1ph;
    s16x8 bl0 = *(const s16x8*)b1pl;
    s16x8 bh1 = *(const s16x8*)(b1ph + 4096);
    s16x8 bl1 = *(const s16x8*)(b1pl + 4096);

    if (tid < 64) {
        int2 v = ((const int2*)eidx)[(size_t)b * NE + e0 + tid];
        int dv = min(max(v.y, 0), NC - 1);
        s_src[tid] = min(max(v.x, 0), NC - 1);
        s_dst[tid] = dv;
        atomicAdd(&counts[b * NC + dv], 1.0f);
    }
    __syncthreads();

    {
        const int row = tid >> 3, c8 = tid & 7;
        const float4* crow = (const float4*)(cell_x + ((size_t)b * NC + s_src[row]) * HID);
        const float4* arow = (const float4*)(eattr + ((size_t)b * NE + e0 + row) * EF);
        #pragma unroll
        for (int i = 0; i < 10; ++i) {
            int c = c8 + i * 8;
            float4 v = (c < 64) ? crow[c] : arow[c - 64];
            *(ushort4*)&Xs[row * XPAD + c * 4] =
                make_ushort4(bf16_rne(v.x), bf16_rne(v.y), bf16_rne(v.z), bf16_rne(v.w));
        }
    }
    __syncthreads();

    f32x16 A0, A1;
    {
        float bias = b1[col];
        #pragma unroll
        for (int r = 0; r < 16; ++r) { A0[r] = bias; A1[r] = bias; }
    }
    for (int t = 0; t < 20; t += 2) {
        s16x8 nh = *(const s16x8*)(b1ph + (size_t)min(t + 2, 19) * 4096);
        s16x8 nl = *(const s16x8*)(b1pl + (size_t)min(t + 2, 19) * 4096);
        int ao = m32 * XPAD + t * 16 + half * 8;
        s16x8 a0 = *(const s16x8*)&Xs[ao];
        s16x8 a1 = *(const s16x8*)&Xs[ao + 32 * XPAD];
        A0 = __builtin_amdgcn_mfma_f32_32x32x16_bf16(a0, bh0, A0, 0, 0, 0);
        A0 = __builtin_amdgcn_mfma_f32_32x32x16_bf16(a0, bl0, A0, 0, 0, 0);
        A1 = __builtin_amdgcn_mfma_f32_32x32x16_bf16(a1, bh0, A1, 0, 0, 0);
        A1 = __builtin_amdgcn_mfma_f32_32x32x16_bf16(a1, bl0, A1, 0, 0, 0);
        bh0 = nh; bl0 = nl;
        nh = *(const s16x8*)(b1ph + (size_t)min(t + 3, 19) * 4096);
        nl = *(const s16x8*)(b1pl + (size_t)min(t + 3, 19) * 4096);
        ao = m32 * XPAD + (t + 1) * 16 + half * 8;
        a0 = *(const s16x8*)&Xs[ao];
        a1 = *(const s16x8*)&Xs[ao + 32 * XPAD];
        A0 = __builtin_amdgcn_mfma_f32_32x32x16_bf16(a0, bh1, A0, 0, 0, 0);
        A0 = __builtin_amdgcn_mfma_f32_32x32x16_bf16(a0, bl1, A0, 0, 0, 0);
        A1 = __builtin_amdgcn_mfma_f32_32x32x16_bf16(a1, bh1, A1, 0, 0, 0);
        A1 = __builtin_amdgcn_mfma_f32_32x32x16_bf16(a1, bl1, A1, 0, 0, 0);
        bh1 = nh; bl1 = nl;
    }

    const ushort_t* b2ph = w2hi + ((size_t)wv * 64 + ln) * 8;
    const ushort_t* b2pl = w2lo + ((size_t)wv * 64 + ln) * 8;
    bh0 = *(const s16x8*)b2ph;
    bl0 = *(const s16x8*)b2pl;
    bh1 = *(const s16x8*)(b2ph + 4096);
    bl1 = *(const s16x8*)(b2pl + 4096);

    __syncthreads();

    #pragma unroll
    for (int r = 0; r < 16; ++r) {
        int row = (r & 3) + 8 * (r >> 2) + 4 * half;
        Xs[row * HPAD + col]        = bf16_rne(fmaxf(A0[r], 0.f));
        Xs[(row + 32) * HPAD + col] = bf16_rne(fmaxf(A1[r], 0.f));
    }
    __syncthreads();

    f32x16 C0, C1;
    {
        float bias = b2[col];
        #pragma unroll
        for (int r = 0; r < 16; ++r) { C0[r] = bias; C1[r] = bias; }
    }
    for (int t = 0; t < 16; t += 2) {
        s16x8 nh = *(const s16x8*)(b2ph + (size_t)min(t + 2, 15) * 4096);
        s16x8 nl = *(const s16x8*)(b2pl + (size_t)min(t + 2, 15) * 4096);
        int ao = m32 * HPAD + t * 16 + half * 8;
        s16x8 a0 = *(const s16x8*)&Xs[ao];
        s16x8 a1 = *(const s16x8*)&Xs[ao + 32 * HPAD];
        C0 = __builtin_amdgcn_mfma_f32_32x32x16_bf16(a0, bh0, C0, 0, 0, 0);
        C0 = __builtin_amdgcn_mfma_f32_32x32x16_bf16(a0, bl0, C0, 0, 0, 0);
        C1 = __builtin_amdgcn_mfma_f32_32x32x16_bf16(a1, bh0, C1, 0, 0, 0);
        C1 = __builtin_amdgcn_mfma_f32_32x32x16_bf16(a1, bl0, C1, 0, 0, 0);
        bh0 = nh; bl0 = nl;
        nh = *(const s16x8*)(b2ph + (size_t)min(t + 3, 15) * 4096);
        nl = *(const s16x8*)(b2pl + (size_t)min(t + 3, 15) * 4096);
        ao = m32 * HPAD + (t + 1) * 16 + half * 8;
        a0 = *(const s16x8*)&Xs[ao];
        a1 = *(const s16x8*)&Xs[ao + 32 * HPAD];
        C0 = __builtin_amdgcn_mfma_f32_32x32x16_bf16(a0, bh1, C0, 0, 0, 0);
        C0 = __builtin_amdgcn_mfma_f32_32x32x16_bf16(a0, bl1, C0, 0, 0, 0);
        C1 = __builtin_amdgcn_mfma_f32_32x32x16_bf16(a1, bh1, C1, 0, 0, 0);
        C1 = __builtin_amdgcn_mfma_f32_32x32x16_bf16(a1, bl1, C1, 0, 0, 0);
        bh1 = nh; bl1 = nl;
    }

    const int colbase = col & ~1;
    const bool evenl = (m32 & 1) == 0;
    #pragma unroll
    for (int r = 0; r < 16; ++r) {
        int row = (r & 3) + 8 * (r >> 2) + 4 * half;
        {
            float other = __shfl_xor(C0[r], 1, 64);
            float vlo = evenl ? C0[r] : other;
            float vhi = evenl ? other : C0[r];
            if (evenl == (r < 8)) {
                unsigned pk = ((unsigned)bf16_rne(vhi) << 16) | (unsigned)bf16_rne(vlo);
                ushort_t* addr = aggbf + ((size_t)b * NC + s_dst[row]) * HID + colbase;
                asm volatile("global_atomic_pk_add_bf16 %0, %1, off"
                             :: "v"(addr), "v"(pk) : "memory");
            }
        }
        {
            float other = __shfl_xor(C1[r], 1, 64);
            float vlo = evenl ? C1[r] : other;
            float vhi = evenl ? other : C1[r];
            if (evenl == (r < 8)) {
                unsigned pk = ((unsigned)bf16_rne(vhi) << 16) | (unsigned)bf16_rne(vlo);
                ushort_t* addr = aggbf + ((size_t)b * NC + s_dst[row + 32]) * HID + colbase;
                asm volatile("global_atomic_pk_add_bf16 %0, %1, off"
                             :: "v"(addr), "v"(pk) : "memory");
            }
        }
    }
}

__global__ __launch_bounds__(512, 6)
void node_kernel_fb(const float* __restrict__ cell_x,
                    const ushort_t* __restrict__ aggbf,
                    const float* __restrict__ counts,
                    const ushort_t* __restrict__ w1hi, const ushort_t* __restrict__ w1lo,
                    const float* __restrict__ b1,
                    const ushort_t* __restrict__ w2hi, const ushort_t* __restrict__ w2lo,
                    const float* __restrict__ b2,
                    const float* __restrict__ gamma, const float* __restrict__ beta,
                    float* __restrict__ out) {
    __shared__ ushort_t Us[32 * UPAD];
    __shared__ float s_inv[32];
    float* hs = (float*)Us;

    const int tid = threadIdx.x;
    const int b   = blockIdx.x >> 7;
    const int r0  = (blockIdx.x & 127) * 32;
    const int wv = tid >> 6, ln = tid & 63;
    const int m32 = ln & 31, half = ln >> 5;
    const int col = wv * 32 + m32;

    const ushort_t* b1ph = w1hi + ((size_t)wv * 64 + ln) * 8;
    const ushort_t* b1pl = w1lo + ((size_t)wv * 64 + ln) * 8;
    s16x8 bhi = *(const s16x8*)b1ph;
    s16x8 blo = *(const s16x8*)b1pl;

    if (tid < 32) {
        float c = counts[b * NC + r0 + tid];
        s_inv[tid] = 1.0f / fmaxf(c, 1.0f);
    }
    __syncthreads();

    {
        const int row = tid >> 4, c8 = tid & 15;
        const float4* crow = (const float4*)(cell_x + ((size_t)b * NC + r0 + row) * HID);
        const ushort4* grow = (const ushort4*)(aggbf + ((size_t)b * NC + r0 + row) * HID);
        float inv = s_inv[row];
        #pragma unroll
        for (int i = 0; i < 8; ++i) {
            int c = c8 + i * 16;
            if (c < 64) {
                float4 v = crow[c];
                *(ushort4*)&Us[row * UPAD + c * 4] =
                    make_ushort4(bf16_rne(v.x), bf16_rne(v.y), bf16_rne(v.z), bf16_rne(v.w));
            } else {
                ushort4 g = grow[c - 64];
                *(ushort4*)&Us[row * UPAD + c * 4] =
                    make_ushort4(bf16_rne(bf16_to_f(g.x) * inv),
                                 bf16_rne(bf16_to_f(g.y) * inv),
                                 bf16_rne(bf16_to_f(g.z) * inv),
                                 bf16_rne(bf16_to_f(g.w) * inv));
            }
        }
    }
    __syncthreads();

    f32x16 acc;
    {
        float bias = b1[col];
        #pragma unroll
        for (int r = 0; r < 16; ++r) acc[r] = bias;
    }
    #pragma unroll 2
    for (int t = 0; t < 32; ++t) {
        int tn1 = (t + 1 < 32) ? t + 1 : 31;
        s16x8 bhin = *(const s16x8*)(b1ph + (size_t)tn1 * 4096);
        s16x8 blon = *(const s16x8*)(b1pl + (size_t)tn1 * 4096);
        s16x8 a = *(const s16x8*)&Us[m32 * UPAD + t * 16 + half * 8];
        acc = __builtin_amdgcn_mfma_f32_32x32x16_bf16(a, bhi, acc, 0, 0, 0);
        acc = __builtin_amdgcn_mfma_f32_32x32x16_bf16(a, blo, acc, 0, 0, 0);
        bhi = bhin; blo = blon;
    }

    const ushort_t* b2ph = w2hi + ((size_t)wv * 64 + ln) * 8;
    const ushort_t* b2pl = w2lo + ((size_t)wv * 64 + ln) * 8;
    bhi = *(const s16x8*)b2ph;
    blo = *(const s16x8*)b2pl;

    __syncthreads();

    #pragma unroll
    for (int r = 0; r < 16; ++r) {
        int row = (r & 3) + 8 * (r >> 2) + 4 * half;
        Us[row * HPAD + col] = bf16_rne(fmaxf(acc[r], 0.f));
    }
    __syncthreads();

    f32x16 c2;
    {
        float bias = b2[col];
        #pragma unroll
        for (int r = 0; r < 16; ++r) c2[r] = bias;
    }
    #pragma unroll 2
    for (int t = 0; t < 16; ++t) {
        int tn1 = (t + 1 < 16) ? t + 1 : 15;
        s16x8 bhin = *(const s16x8*)(b2ph + (size_t)tn1 * 4096);
        s16x8 blon = *(const s16x8*)(b2pl + (size_t)tn1 * 4096);
        s16x8 a = *(const s16x8*)&Us[m32 * HPAD + t * 16 + half * 8];
        c2 = __builtin_amdgcn_mfma_f32_32x32x16_bf16(a, bhi, c2, 0, 0, 0);
        c2 = __builtin_amdgcn_mfma_f32_32x32x16_bf16(a, blo, c2, 0, 0, 0);
        bhi = bhin; blo = blon;
    }
    __syncthreads();

    #pragma unroll
    for (int r = 0; r < 16; ++r) {
        int row = (r & 3) + 8 * (r >> 2) + 4 * half;
        float cx = cell_x[((size_t)b * NC + r0 + row) * HID + col];
        hs[row * HSF + col] = c2[r] + cx;
    }
    __syncthreads();

    #pragma unroll
    for (int i = 0; i < 4; ++i) {
        int r = wv * 4 + i;
        float v[4];
        float s = 0.f, q = 0.f;
        #pragma unroll
        for (int j = 0; j < 4; ++j) {
            v[j] = hs[r * HSF + ln + 64 * j];
            s += v[j];
            q = fmaf(v[j], v[j], q);
        }
        #pragma unroll
        for (int off = 32; off > 0; off >>= 1) {
            s += __shfl_xor(s, off, 64);
            q += __shfl_xor(q, off, 64);
        }
        float mu = s * (1.0f / HID);
        float var = q * (1.0f / HID) - mu * mu;
        float rs = rsqrtf(var + EPSV);
        float* orow = out + ((size_t)b * NC + r0 + r) * HID;
        #pragma unroll
        for (int j = 0; j < 4; ++j) {
            int c = ln + 64 * j;
            orow[c] = (v[j] - mu) * rs * gamma[c] + beta[c];
        }
    }
}

extern "C" void kernel_launch(void* const* d_in, const int* in_sizes, int n_in,
                              void* d_out, int out_size, void* d_ws, size_t ws_size,
                              hipStream_t stream) {
    const float* cell_x = (const float*)d_in[0];
    const int*   eidx   = (const int*)d_in[1];
    const float* eattr  = (const float*)d_in[2];
    const float* mW1    = (const float*)d_in[3];
    const float* mb1    = (const float*)d_in[4];
    const float* mW2    = (const float*)d_in[5];
    const float* mb2    = (const float*)d_in[6];
    const float* uW1    = (const float*)d_in[7];
    const float* ub1    = (const float*)d_in[8];
    const float* uW2    = (const float*)d_in[9];
    const float* ub2    = (const float*)d_in[10];
    const float* gamma  = (const float*)d_in[11];
    const float* beta   = (const float*)d_in[12];
    float* out = (float*)d_out;

    ushort_t* aggbf = (ushort_t*)d_ws;                   // [B, NC, HID] bf16 (8 MB)
    float* counts = (float*)(aggbf + (size_t)BSZ * NC * HID);   // [B, NC]
    ushort_t* w1hi = (ushort_t*)(counts + BSZ * NC);     // packed mW1: 320*256
    ushort_t* w1lo = w1hi + KIN * HID;
    ushort_t* w2hi = w1lo + KIN * HID;                   // packed mW2: 256*256
    ushort_t* w2lo = w2hi + HID * HID;
    ushort_t* u1hi = w2lo + HID * HID;                   // packed uW1: 512*256
    ushort_t* u1lo = u1hi + 2 * HID * HID;
    ushort_t* u2hi = u1lo + 2 * HID * HID;               // packed uW2: 256*256
    ushort_t* u2lo = u2hi + HID * HID;
    float* Pmat = (float*)(u2lo + HID * HID);            // [B*NC, 512] fp32 (32 MB)

    // byte offset of end of Pmat relative to d_ws
    size_t p_off  = (size_t)((char*)Pmat - (char*)d_ws);
    size_t p_need = p_off + sizeof(float) * (size_t)BSZ * NC * PSTR;
    bool useP = (ws_size >= p_need);

    // zero aggbf (bf16) + counts (fp32): bytes = B*NC*HID*2 + B*NC*4
    int n4 = (BSZ * NC * HID * 2 + BSZ * NC * 4) / 16;
    prep_kernel<<<PACKB + ZEROB, 256, 0, stream>>>(
        mW1, mW2, uW1, uW2, w1hi, w1lo, w2hi, w2lo, u1hi, u1lo, u2hi, u2lo,
        (float4*)d_ws, n4);

    if (useP) {
        pre_kernel<<<BSZ * NC / 32, 512, 0, stream>>>(cell_x, w1hi, w1lo, u1hi, u1lo, Pmat);
        edge_kernel<<<BSZ * NE / 64, 512, 0, stream>>>(Pmat, eidx, eattr,
                                                       w1hi, w1lo, mb1, w2hi, w2lo, mb2,
                                                       aggbf, counts);
        node_kernel<<<BSZ * NC / 32, 512, 0, stream>>>(cell_x, aggbf, counts, Pmat,
                                                       u1hi, u1lo, ub1, u2hi, u2lo, ub2,
                                                       gamma, beta, out);
    } else {
        edge_kernel_fb<<<BSZ * NE / 64, 512, 0, stream>>>(cell_x, eidx, eattr,
                                                          w1hi, w1lo, mb1, w2hi, w2lo, mb2,
                                                          aggbf, counts);
        node_kernel_fb<<<BSZ * NC / 32, 512, 0, stream>>>(cell_x, aggbf, counts,
                                                          u1hi, u1lo, ub1, u2hi, u2lo, ub2,
                                                          gamma, beta, out);
    }
}

// Round 3
// 344.588 us; speedup vs baseline: 1.0070x; 1.0070x over previous
//
#include <hip/hip_runtime.h>

#define HID 256
#define EF  64
#define KIN 320      // HID + EF
#define NC  4096
#define NE  65536
#define BSZ 4
#define EPSV 1e-5f

typedef unsigned short ushort_t;
typedef __attribute__((ext_vector_type(8))) short s16x8;
typedef __attribute__((ext_vector_type(16))) float f32x16;

// LDS strides in ushort elements
#define EPAD 72      // edge-attr tile row: 144 B
#define HPAD 264     // hidden/msg tile row: 528 B
#define UPAD 520     // node LDS pool row: 1040 B
#define HSF  260     // node h (fp32) stride

// round-to-nearest-even fp32 -> bf16 (as ushort bits)
__device__ __forceinline__ ushort_t bf16_rne(float f) {
    unsigned u = __float_as_uint(f);
    return (ushort_t)((u + 0x7fffu + ((u >> 16) & 1u)) >> 16);
}
__device__ __forceinline__ float bf16_to_f(ushort_t u) {
    return __uint_as_float(((unsigned)u) << 16);
}
// truncating hi/lo split (pair sums to ~fp32 precision) — for weights (B operand)
__device__ __forceinline__ void split_bf16(float v, ushort_t& h, ushort_t& l) {
    unsigned u = __float_as_uint(v);
    h = (ushort_t)(u >> 16);
    float hf = __uint_as_float(u & 0xffff0000u);
    l = (ushort_t)(__float_as_uint(v - hf) >> 16);
}

// Pack weights into 32x32x16 MFMA B-fragment order, hi/lo bf16.
// frag idx = (t*8 + nt)*64 + lane; elem j: W[t*16 + (lane>>5)*8 + j][nt*32 + (lane&31)]
__device__ __forceinline__ void pack_one(const float* W, int idx,
                                         ushort_t* hi, ushort_t* lo) {
    int l = idx & 63;
    int tn = idx >> 6;
    int nt = tn & 7, t = tn >> 3;
    int k0 = t * 16 + (l >> 5) * 8;
    int col = nt * 32 + (l & 31);
    #pragma unroll
    for (int j = 0; j < 8; ++j) {
        float v = W[(size_t)(k0 + j) * 256 + col];
        ushort_t h, lw;
        split_bf16(v, h, lw);
        hi[(size_t)idx * 8 + j] = h;
        lo[(size_t)idx * 8 + j] = lw;
    }
}

#define FR1 10240    // (320/16)*8*64
#define FR2 8192     // (256/16)*8*64
#define FR3 16384    // (512/16)*8*64
#define PACKB 168    // ceil((FR1+2*FR2+FR3)/256)
#define ZEROB 256    // blocks for the zero path

// blocks [0,PACKB): pack weights; blocks [PACKB, PACKB+ZEROB): zero aggf+counts
__global__ __launch_bounds__(256)
void prep_kernel(const float* __restrict__ mW1, const float* __restrict__ mW2,
                 const float* __restrict__ uW1, const float* __restrict__ uW2,
                 ushort_t* __restrict__ w1hi, ushort_t* __restrict__ w1lo,
                 ushort_t* __restrict__ w2hi, ushort_t* __restrict__ w2lo,
                 ushort_t* __restrict__ u1hi, ushort_t* __restrict__ u1lo,
                 ushort_t* __restrict__ u2hi, ushort_t* __restrict__ u2lo,
                 float4* __restrict__ zp, int n4) {
    if (blockIdx.x >= PACKB) {
        int i = (blockIdx.x - PACKB) * 256 + threadIdx.x;
        int stride = ZEROB * 256;
        float4 z = make_float4(0.f, 0.f, 0.f, 0.f);
        for (; i < n4; i += stride) zp[i] = z;
        return;
    }
    int idx = blockIdx.x * 256 + threadIdx.x;
    if (idx < FR1) { pack_one(mW1, idx, w1hi, w1lo); return; }
    idx -= FR1;
    if (idx < FR2) { pack_one(mW2, idx, w2hi, w2lo); return; }
    idx -= FR2;
    if (idx < FR3) { pack_one(uW1, idx, u1hi, u1lo); return; }
    idx -= FR3;
    if (idx < FR2) { pack_one(uW2, idx, u2hi, u2lo); return; }
}

// ---- counting sort of edges by dst (per batch) ----
__global__ __launch_bounds__(256)
void hist_kernel(const int* __restrict__ eidx, float* __restrict__ counts) {
    int i = blockIdx.x * 256 + threadIdx.x;      // < BSZ*NE
    int b = i >> 16;
    int2 v = ((const int2*)eidx)[i];
    int d = min(max(v.y, 0), NC - 1);
    atomicAdd(&counts[b * NC + d], 1.0f);
}

__global__ __launch_bounds__(1024)
void scan_kernel(const float* __restrict__ counts, int* __restrict__ woff) {
    __shared__ int wsum[16];
    int b = blockIdx.x, t = threadIdx.x;         // 1024 threads, 4 bins each
    int base = b * NC + t * 4;
    int v0 = (int)counts[base],     v1 = (int)counts[base + 1];
    int v2 = (int)counts[base + 2], v3 = (int)counts[base + 3];
    int ts = v0 + v1 + v2 + v3;
    int lane = t & 63;
    int x = ts;
    #pragma unroll
    for (int off = 1; off < 64; off <<= 1) {
        int y = __shfl_up(x, off, 64);
        if (lane >= off) x += y;
    }
    if (lane == 63) wsum[t >> 6] = x;
    __syncthreads();
    if (t == 0) {
        int s = 0;
        #pragma unroll
        for (int w = 0; w < 16; ++w) { int tmp = wsum[w]; wsum[w] = s; s += tmp; }
    }
    __syncthreads();
    int excl = wsum[t >> 6] + (x - ts);
    woff[base]     = excl;
    woff[base + 1] = excl + v0;
    woff[base + 2] = excl + v0 + v1;
    woff[base + 3] = excl + v0 + v1 + v2;
}

__global__ __launch_bounds__(256)
void scatter_kernel(const int* __restrict__ eidx, int* __restrict__ woff,
                    int* __restrict__ sorted) {
    int i = blockIdx.x * 256 + threadIdx.x;      // < BSZ*NE
    int b = i >> 16, e = i & (NE - 1);
    int2 v = ((const int2*)eidx)[i];
    int d = min(max(v.y, 0), NC - 1);
    int pos = atomicAdd(&woff[b * NC + d], 1);
    sorted[(size_t)b * NE + pos] = e;
}

// ======================= P precompute =======================
// Pe = cell_x @ mW1[:256,:] (fp32), Pn = cell_x @ uW1[:256,:] (bf16)
__global__ __launch_bounds__(512, 6)
void pre_kernel(const float* __restrict__ cell_x,
                const ushort_t* __restrict__ w1hi, const ushort_t* __restrict__ w1lo,
                const ushort_t* __restrict__ u1hi, const ushort_t* __restrict__ u1lo,
                float* __restrict__ Pe, ushort_t* __restrict__ Pn) {
    __shared__ ushort_t Us[32 * HPAD];   // 16,896 B

    const int tid = threadIdx.x;
    const size_t r0 = (size_t)blockIdx.x * 32;     // global row in [0, B*NC)
    const int wv = tid >> 6, ln = tid & 63;
    const int m32 = ln & 31, half = ln >> 5;
    const int col = wv * 32 + m32;

    const ushort_t* wph = w1hi + ((size_t)wv * 64 + ln) * 8;
    const ushort_t* wpl = w1lo + ((size_t)wv * 64 + ln) * 8;
    const ushort_t* uph = u1hi + ((size_t)wv * 64 + ln) * 8;
    const ushort_t* upl = u1lo + ((size_t)wv * 64 + ln) * 8;
    s16x8 wh = *(const s16x8*)wph, wl = *(const s16x8*)wpl;
    s16x8 uh = *(const s16x8*)uph, ul = *(const s16x8*)upl;

    // stage cell_x rows as RNE bf16
    {
        const int row = tid >> 4, c8 = tid & 15;
        const float4* crow = (const float4*)(cell_x + (r0 + row) * HID);
        #pragma unroll
        for (int i = 0; i < 4; ++i) {
            int c = c8 + i * 16;
            float4 v = crow[c];
            *(ushort4*)&Us[row * HPAD + c * 4] =
                make_ushort4(bf16_rne(v.x), bf16_rne(v.y), bf16_rne(v.z), bf16_rne(v.w));
        }
    }
    __syncthreads();

    f32x16 aw, au;
    #pragma unroll
    for (int r = 0; r < 16; ++r) { aw[r] = 0.f; au[r] = 0.f; }

    #pragma unroll 2
    for (int t = 0; t < 16; ++t) {
        int tn = (t + 1 < 16) ? t + 1 : 15;
        s16x8 whn = *(const s16x8*)(wph + (size_t)tn * 4096);
        s16x8 wln = *(const s16x8*)(wpl + (size_t)tn * 4096);
        s16x8 uhn = *(const s16x8*)(uph + (size_t)tn * 4096);
        s16x8 uln = *(const s16x8*)(upl + (size_t)tn * 4096);
        s16x8 a = *(const s16x8*)&Us[m32 * HPAD + t * 16 + half * 8];
        aw = __builtin_amdgcn_mfma_f32_32x32x16_bf16(a, wh, aw, 0, 0, 0);
        aw = __builtin_amdgcn_mfma_f32_32x32x16_bf16(a, wl, aw, 0, 0, 0);
        au = __builtin_amdgcn_mfma_f32_32x32x16_bf16(a, uh, au, 0, 0, 0);
        au = __builtin_amdgcn_mfma_f32_32x32x16_bf16(a, ul, au, 0, 0, 0);
        wh = whn; wl = wln; uh = uhn; ul = uln;
    }

    #pragma unroll
    for (int r = 0; r < 16; ++r) {
        int row = (r & 3) + 8 * (r >> 2) + 4 * half;
        Pe[(r0 + row) * 256 + col] = aw[r];
        Pn[(r0 + row) * 256 + col] = bf16_rne(au[r]);
    }
}

// 64 sorted edges/block, 512 threads = 8 waves; wave wv owns n-tile wv, 2 m-tiles
__global__ __launch_bounds__(512, 6)
void edge_kernel(const float* __restrict__ Pe,
                 const int*   __restrict__ eidx,
                 const int*   __restrict__ sorted,
                 const float* __restrict__ eattr,
                 const ushort_t* __restrict__ w1hi, const ushort_t* __restrict__ w1lo,
                 const float* __restrict__ b1,
                 const ushort_t* __restrict__ w2hi, const ushort_t* __restrict__ w2lo,
                 const float* __restrict__ b2,
                 float* __restrict__ aggf) {
    __shared__ ushort_t Xs[64 * HPAD];   // 33,792 B; staging uses EPAD sub-layout
    __shared__ int s_src[64], s_dst[64], s_eid[64];

    const int tid = threadIdx.x;
    const int b   = blockIdx.x >> 10;            // 1024 blocks per batch
    const int e0  = (blockIdx.x & 1023) * 64;
    const int wv = tid >> 6, ln = tid & 63;
    const int m32 = ln & 31, half = ln >> 5;
    const int col = wv * 32 + m32;

    // ---- hoisted W1b (eattr-part, packed t=16..19) B-prefetch ----
    const ushort_t* b1ph = w1hi + ((size_t)(16 * 8 + wv) * 64 + ln) * 8;
    const ushort_t* b1pl = w1lo + ((size_t)(16 * 8 + wv) * 64 + ln) * 8;
    s16x8 bh0 = *(const s16x8*)b1ph;
    s16x8 bl0 = *(const s16x8*)b1pl;
    s16x8 bh1 = *(const s16x8*)(b1ph + 4096);
    s16x8 bl1 = *(const s16x8*)(b1pl + 4096);

    if (tid < 64) {
        int eid = sorted[(size_t)b * NE + e0 + tid];
        s_eid[tid] = eid;
        int2 v = ((const int2*)eidx)[(size_t)b * NE + eid];
        s_src[tid] = min(max(v.x, 0), NC - 1);
        s_dst[tid] = min(max(v.y, 0), NC - 1);
    }
    __syncthreads();

    // ---- stage eattr (64x64, gathered rows) as RNE bf16 ----
    {
        const int row = tid >> 3, c8 = tid & 7;
        const float4* arow = (const float4*)(eattr + ((size_t)b * NE + s_eid[row]) * EF);
        #pragma unroll
        for (int i = 0; i < 2; ++i) {
            int c = c8 + i * 8;                  // float4 index 0..15
            float4 v = arow[c];
            *(ushort4*)&Xs[row * EPAD + c * 4] =
                make_ushort4(bf16_rne(v.x), bf16_rne(v.y), bf16_rne(v.z), bf16_rne(v.w));
        }
    }
    __syncthreads();

    // ---- GEMM1': acc = eattr @ W1b + b1, K=64 ----
    f32x16 A0, A1;
    {
        float bias = b1[col];
        #pragma unroll
        for (int r = 0; r < 16; ++r) { A0[r] = bias; A1[r] = bias; }
    }
    #pragma unroll
    for (int t = 0; t < 4; t += 2) {
        s16x8 nh = *(const s16x8*)(b1ph + (size_t)min(t + 2, 3) * 4096);
        s16x8 nl = *(const s16x8*)(b1pl + (size_t)min(t + 2, 3) * 4096);
        int ao = m32 * EPAD + t * 16 + half * 8;
        s16x8 a0 = *(const s16x8*)&Xs[ao];
        s16x8 a1 = *(const s16x8*)&Xs[ao + 32 * EPAD];
        A0 = __builtin_amdgcn_mfma_f32_32x32x16_bf16(a0, bh0, A0, 0, 0, 0);
        A0 = __builtin_amdgcn_mfma_f32_32x32x16_bf16(a0, bl0, A0, 0, 0, 0);
        A1 = __builtin_amdgcn_mfma_f32_32x32x16_bf16(a1, bh0, A1, 0, 0, 0);
        A1 = __builtin_amdgcn_mfma_f32_32x32x16_bf16(a1, bl0, A1, 0, 0, 0);
        bh0 = nh; bl0 = nl;
        nh = *(const s16x8*)(b1ph + (size_t)min(t + 3, 3) * 4096);
        nl = *(const s16x8*)(b1pl + (size_t)min(t + 3, 3) * 4096);
        ao = m32 * EPAD + (t + 1) * 16 + half * 8;
        a0 = *(const s16x8*)&Xs[ao];
        a1 = *(const s16x8*)&Xs[ao + 32 * EPAD];
        A0 = __builtin_amdgcn_mfma_f32_32x32x16_bf16(a0, bh1, A0, 0, 0, 0);
        A0 = __builtin_amdgcn_mfma_f32_32x32x16_bf16(a0, bl1, A0, 0, 0, 0);
        A1 = __builtin_amdgcn_mfma_f32_32x32x16_bf16(a1, bh1, A1, 0, 0, 0);
        A1 = __builtin_amdgcn_mfma_f32_32x32x16_bf16(a1, bl1, A1, 0, 0, 0);
        bh1 = nh; bl1 = nl;
    }

    // ---- add gathered Pe[src] (fp32, coalesced in col; rows L2/L3-resident) ----
    {
        const float* pb = Pe + (size_t)b * NC * 256 + col;
        #pragma unroll
        for (int r = 0; r < 16; ++r) {
            int rw = (r & 3) + 8 * (r >> 2) + 4 * half;
            A0[r] += pb[(size_t)s_src[rw] * 256];
            A1[r] += pb[(size_t)s_src[rw + 32] * 256];
        }
    }

    // ---- hoisted W2 B-prefetch ----
    const ushort_t* b2ph = w2hi + ((size_t)wv * 64 + ln) * 8;
    const ushort_t* b2pl = w2lo + ((size_t)wv * 64 + ln) * 8;
    bh0 = *(const s16x8*)b2ph;
    bl0 = *(const s16x8*)b2pl;
    bh1 = *(const s16x8*)(b2ph + 4096);
    bl1 = *(const s16x8*)(b2pl + 4096);

    __syncthreads();   // all eattr reads done; reuse LDS for H

    // ---- relu + RNE bf16 + store hidden (rows = edges) ----
    #pragma unroll
    for (int r = 0; r < 16; ++r) {
        int row = (r & 3) + 8 * (r >> 2) + 4 * half;
        Xs[row * HPAD + col]        = bf16_rne(fmaxf(A0[r], 0.f));
        Xs[(row + 32) * HPAD + col] = bf16_rne(fmaxf(A1[r], 0.f));
    }
    __syncthreads();

    // ---- GEMM2: msg = hidden @ W2 + b2, K=256 ----
    f32x16 C0, C1;
    {
        float bias = b2[col];
        #pragma unroll
        for (int r = 0; r < 16; ++r) { C0[r] = bias; C1[r] = bias; }
    }
    for (int t = 0; t < 16; t += 2) {
        s16x8 nh = *(const s16x8*)(b2ph + (size_t)min(t + 2, 15) * 4096);
        s16x8 nl = *(const s16x8*)(b2pl + (size_t)min(t + 2, 15) * 4096);
        int ao = m32 * HPAD + t * 16 + half * 8;
        s16x8 a0 = *(const s16x8*)&Xs[ao];
        s16x8 a1 = *(const s16x8*)&Xs[ao + 32 * HPAD];
        C0 = __builtin_amdgcn_mfma_f32_32x32x16_bf16(a0, bh0, C0, 0, 0, 0);
        C0 = __builtin_amdgcn_mfma_f32_32x32x16_bf16(a0, bl0, C0, 0, 0, 0);
        C1 = __builtin_amdgcn_mfma_f32_32x32x16_bf16(a1, bh0, C1, 0, 0, 0);
        C1 = __builtin_amdgcn_mfma_f32_32x32x16_bf16(a1, bl0, C1, 0, 0, 0);
        bh0 = nh; bl0 = nl;
        nh = *(const s16x8*)(b2ph + (size_t)min(t + 3, 15) * 4096);
        nl = *(const s16x8*)(b2pl + (size_t)min(t + 3, 15) * 4096);
        ao = m32 * HPAD + (t + 1) * 16 + half * 8;
        a0 = *(const s16x8*)&Xs[ao];
        a1 = *(const s16x8*)&Xs[ao + 32 * HPAD];
        C0 = __builtin_amdgcn_mfma_f32_32x32x16_bf16(a0, bh1, C0, 0, 0, 0);
        C0 = __builtin_amdgcn_mfma_f32_32x32x16_bf16(a0, bl1, C0, 0, 0, 0);
        C1 = __builtin_amdgcn_mfma_f32_32x32x16_bf16(a1, bh1, C1, 0, 0, 0);
        C1 = __builtin_amdgcn_mfma_f32_32x32x16_bf16(a1, bl1, C1, 0, 0, 0);
        bh1 = nh; bl1 = nl;
    }

    __syncthreads();   // H reads done; reuse LDS for msg tile

    // ---- store msg tile (bf16) ----
    #pragma unroll
    for (int r = 0; r < 16; ++r) {
        int row = (r & 3) + 8 * (r >> 2) + 4 * half;
        Xs[row * HPAD + col]        = bf16_rne(C0[r]);
        Xs[(row + 32) * HPAD + col] = bf16_rne(C1[r]);
    }
    __syncthreads();

    // ---- segment-reduce over sorted dst runs; fp32 atomics, wave-uniform branch ----
    {
        const int c = tid & 255;
        const int seg = tid >> 8;                // waves 0-3: rows 0..31; 4-7: 32..63
        const int rbase = seg * 32;
        float s = bf16_to_f(Xs[rbase * HPAD + c]);
        int cur = s_dst[rbase];
        for (int i = 1; i < 32; ++i) {
            int rr = rbase + i;
            float v = bf16_to_f(Xs[rr * HPAD + c]);
            int d = s_dst[rr];
            if (d != cur) {
                atomicAdd(&aggf[((size_t)b * NC + cur) * HID + c], s);
                cur = d; s = v;
            } else {
                s += v;
            }
        }
        atomicAdd(&aggf[((size_t)b * NC + cur) * HID + c], s);
    }
}

// 32 nodes/block, 512 threads = 8 waves; wave wv owns n-tile wv, 1 m-tile
__global__ __launch_bounds__(512, 6)
void node_kernel(const float* __restrict__ cell_x,
                 const float* __restrict__ aggf,
                 const float* __restrict__ counts,
                 const ushort_t* __restrict__ Pn,
                 const ushort_t* __restrict__ u1hi, const ushort_t* __restrict__ u1lo,
                 const float* __restrict__ b1,
                 const ushort_t* __restrict__ u2hi, const ushort_t* __restrict__ u2lo,
                 const float* __restrict__ b2,
                 const float* __restrict__ gamma, const float* __restrict__ beta,
                 float* __restrict__ out) {
    __shared__ ushort_t Us[32 * UPAD];   // pool: agg/H bf16 (32*HPAD) + hs fp32 overlay
    __shared__ float s_inv[32];
    float* hs = (float*)Us;

    const int tid = threadIdx.x;
    const int b   = blockIdx.x >> 7;             // 128 blocks per batch
    const int r0  = (blockIdx.x & 127) * 32;
    const int wv = tid >> 6, ln = tid & 63;
    const int m32 = ln & 31, half = ln >> 5;
    const int col = wv * 32 + m32;

    // hoisted uW1b (agg-part, packed t=16..31) B-prefetch
    const ushort_t* b1ph = u1hi + ((size_t)(16 * 8 + wv) * 64 + ln) * 8;
    const ushort_t* b1pl = u1lo + ((size_t)(16 * 8 + wv) * 64 + ln) * 8;
    s16x8 bhi = *(const s16x8*)b1ph;
    s16x8 blo = *(const s16x8*)b1pl;

    if (tid < 32) {
        float c = counts[b * NC + r0 + tid];
        s_inv[tid] = 1.0f / fmaxf(c, 1.0f);
    }
    __syncthreads();

    // ---- stage agg*inv (fp32 -> RNE bf16), 32 x 256 ----
    {
        const int row = tid >> 4, c8 = tid & 15;
        const float4* grow = (const float4*)(aggf + ((size_t)b * NC + r0 + row) * HID);
        float inv = s_inv[row];
        #pragma unroll
        for (int i = 0; i < 4; ++i) {
            int c = c8 + i * 16;                 // float4 group index 0..63
            float4 g = grow[c];
            *(ushort4*)&Us[row * HPAD + c * 4] =
                make_ushort4(bf16_rne(g.x * inv), bf16_rne(g.y * inv),
                             bf16_rne(g.z * inv), bf16_rne(g.w * inv));
        }
    }
    __syncthreads();

    // ---- GEMM1': acc = agg @ uW1b + ub1, K=256 ----
    f32x16 acc;
    {
        float bias = b1[col];
        #pragma unroll
        for (int r = 0; r < 16; ++r) acc[r] = bias;
    }
    #pragma unroll 2
    for (int t = 0; t < 16; ++t) {
        int tn1 = (t + 1 < 16) ? t + 1 : 15;
        s16x8 bhin = *(const s16x8*)(b1ph + (size_t)tn1 * 4096);
        s16x8 blon = *(const s16x8*)(b1pl + (size_t)tn1 * 4096);
        s16x8 a = *(const s16x8*)&Us[m32 * HPAD + t * 16 + half * 8];
        acc = __builtin_amdgcn_mfma_f32_32x32x16_bf16(a, bhi, acc, 0, 0, 0);
        acc = __builtin_amdgcn_mfma_f32_32x32x16_bf16(a, blo, acc, 0, 0, 0);
        bhi = bhin; blo = blon;
    }

    // ---- add Pn (cell_x @ uW1a half; bf16, contiguous rows) ----
    {
        const ushort_t* pb = Pn + ((size_t)b * NC + r0) * 256 + col;
        #pragma unroll
        for (int r = 0; r < 16; ++r) {
            int row = (r & 3) + 8 * (r >> 2) + 4 * half;
            acc[r] += bf16_to_f(pb[(size_t)row * 256]);
        }
    }

    // hoisted uW2 B-prefetch (before repack barrier)
    const ushort_t* b2ph = u2hi + ((size_t)wv * 64 + ln) * 8;
    const ushort_t* b2pl = u2lo + ((size_t)wv * 64 + ln) * 8;
    bhi = *(const s16x8*)b2ph;
    blo = *(const s16x8*)b2pl;

    __syncthreads();   // agg tile dead; reuse for H

    #pragma unroll
    for (int r = 0; r < 16; ++r) {
        int row = (r & 3) + 8 * (r >> 2) + 4 * half;
        Us[row * HPAD + col] = bf16_rne(fmaxf(acc[r], 0.f));
    }
    __syncthreads();

    // ---- GEMM2: o = hidden @ uW2 + ub2, K=256 ----
    f32x16 c2;
    {
        float bias = b2[col];
        #pragma unroll
        for (int r = 0; r < 16; ++r) c2[r] = bias;
    }
    #pragma unroll 2
    for (int t = 0; t < 16; ++t) {
        int tn1 = (t + 1 < 16) ? t + 1 : 15;
        s16x8 bhin = *(const s16x8*)(b2ph + (size_t)tn1 * 4096);
        s16x8 blon = *(const s16x8*)(b2pl + (size_t)tn1 * 4096);
        s16x8 a = *(const s16x8*)&Us[m32 * HPAD + t * 16 + half * 8];
        c2 = __builtin_amdgcn_mfma_f32_32x32x16_bf16(a, bhi, c2, 0, 0, 0);
        c2 = __builtin_amdgcn_mfma_f32_32x32x16_bf16(a, blo, c2, 0, 0, 0);
        bhi = bhin; blo = blon;
    }
    __syncthreads();   // H dead; reuse pool for hs (fp32)

    // ---- residual: h = cell_x + o ----
    #pragma unroll
    for (int r = 0; r < 16; ++r) {
        int row = (r & 3) + 8 * (r >> 2) + 4 * half;
        float cx = cell_x[((size_t)b * NC + r0 + row) * HID + col];
        hs[row * HSF + col] = c2[r] + cx;
    }
    __syncthreads();

    // ---- LayerNorm per row: wave wv handles rows wv*4..+3 ----
    #pragma unroll
    for (int i = 0; i < 4; ++i) {
        int r = wv * 4 + i;
        float v[4];
        float s = 0.f, q = 0.f;
        #pragma unroll
        for (int j = 0; j < 4; ++j) {
            v[j] = hs[r * HSF + ln + 64 * j];
            s += v[j];
            q = fmaf(v[j], v[j], q);
        }
        #pragma unroll
        for (int off = 32; off > 0; off >>= 1) {
            s += __shfl_xor(s, off, 64);
            q += __shfl_xor(q, off, 64);
        }
        float mu = s * (1.0f / HID);
        float var = q * (1.0f / HID) - mu * mu;
        float rs = rsqrtf(var + EPSV);
        float* orow = out + ((size_t)b * NC + r0 + r) * HID;
        #pragma unroll
        for (int j = 0; j < 4; ++j) {
            int c = ln + 64 * j;
            orow[c] = (v[j] - mu) * rs * gamma[c] + beta[c];
        }
    }
}

extern "C" void kernel_launch(void* const* d_in, const int* in_sizes, int n_in,
                              void* d_out, int out_size, void* d_ws, size_t ws_size,
                              hipStream_t stream) {
    const float* cell_x = (const float*)d_in[0];
    const int*   eidx   = (const int*)d_in[1];
    const float* eattr  = (const float*)d_in[2];
    const float* mW1    = (const float*)d_in[3];
    const float* mb1    = (const float*)d_in[4];
    const float* mW2    = (const float*)d_in[5];
    const float* mb2    = (const float*)d_in[6];
    const float* uW1    = (const float*)d_in[7];
    const float* ub1    = (const float*)d_in[8];
    const float* uW2    = (const float*)d_in[9];
    const float* ub2    = (const float*)d_in[10];
    const float* gamma  = (const float*)d_in[11];
    const float* beta   = (const float*)d_in[12];
    float* out = (float*)d_out;

    // workspace layout (~41.8 MB; harness proven >= 43.35 MB)
    float* aggf   = (float*)d_ws;                        // [B,NC,HID] fp32, 16 MB
    float* counts = aggf + (size_t)BSZ * NC * HID;       // [B,NC] fp32, 64 KB
    int*   woff   = (int*)(counts + BSZ * NC);           // [B,NC] int, 64 KB
    int*   sorted = woff + BSZ * NC;                     // [B,NE] int, 1 MB
    ushort_t* w1hi = (ushort_t*)(sorted + (size_t)BSZ * NE);
    ushort_t* w1lo = w1hi + KIN * HID;
    ushort_t* w2hi = w1lo + KIN * HID;
    ushort_t* w2lo = w2hi + HID * HID;
    ushort_t* u1hi = w2lo + HID * HID;
    ushort_t* u1lo = u1hi + 2 * HID * HID;
    ushort_t* u2hi = u1lo + 2 * HID * HID;
    ushort_t* u2lo = u2hi + HID * HID;
    float*    Pe   = (float*)(u2lo + HID * HID);         // [B*NC,256] fp32, 16 MB
    ushort_t* Pn   = (ushort_t*)(Pe + (size_t)BSZ * NC * 256); // [B*NC,256] bf16, 8 MB

    // zero aggf + counts (contiguous): bytes = B*NC*HID*4 + B*NC*4
    int n4 = (BSZ * NC * HID * 4 + BSZ * NC * 4) / 16;
    prep_kernel<<<PACKB + ZEROB, 256, 0, stream>>>(
        mW1, mW2, uW1, uW2, w1hi, w1lo, w2hi, w2lo, u1hi, u1lo, u2hi, u2lo,
        (float4*)d_ws, n4);
    hist_kernel<<<BSZ * NE / 256, 256, 0, stream>>>(eidx, counts);
    scan_kernel<<<BSZ, 1024, 0, stream>>>(counts, woff);
    scatter_kernel<<<BSZ * NE / 256, 256, 0, stream>>>(eidx, woff, sorted);
    pre_kernel<<<BSZ * NC / 32, 512, 0, stream>>>(cell_x, w1hi, w1lo, u1hi, u1lo, Pe, Pn);
    edge_kernel<<<BSZ * NE / 64, 512, 0, stream>>>(Pe, eidx, sorted, eattr,
                                                   w1hi, w1lo, mb1, w2hi, w2lo, mb2,
                                                   aggf);
    node_kernel<<<BSZ * NC / 32, 512, 0, stream>>>(cell_x, aggf, counts, Pn,
                                                   u1hi, u1lo, ub1, u2hi, u2lo, ub2,
                                                   gamma, beta, out);
}

// Round 4
// 307.943 us; speedup vs baseline: 1.1269x; 1.1190x over previous
//
#include <hip/hip_runtime.h>

#define HID 256
#define EF  64
#define KIN 320      // HID + EF
#define NC  4096
#define NE  65536
#define BSZ 4
#define EPSV 1e-5f

typedef unsigned short ushort_t;
typedef __attribute__((ext_vector_type(8))) short s16x8;
typedef __attribute__((ext_vector_type(16))) float f32x16;

// LDS strides in ushort elements.
// HPAD=260: A-frag stride 130 words ≡ 2 (mod 32) -> 2-way bank alias (free).
// EPAD=68:  stride 34 words ≡ 2 (mod 32) -> 2-way (free).  (264/72 were 4-way.)
#define EPAD 68      // edge-attr tile row: 136 B
#define HPAD 260     // hidden tile row: 520 B
#define UPAD 520     // node LDS pool row: 1040 B
#define HSF  260     // node h (fp32) stride

// round-to-nearest-even fp32 -> bf16 (as ushort bits)
__device__ __forceinline__ ushort_t bf16_rne(float f) {
    unsigned u = __float_as_uint(f);
    return (ushort_t)((u + 0x7fffu + ((u >> 16) & 1u)) >> 16);
}
__device__ __forceinline__ float bf16_to_f(ushort_t u) {
    return __uint_as_float(((unsigned)u) << 16);
}
// truncating hi/lo split (pair sums to ~fp32 precision) — for weights (B operand)
__device__ __forceinline__ void split_bf16(float v, ushort_t& h, ushort_t& l) {
    unsigned u = __float_as_uint(v);
    h = (ushort_t)(u >> 16);
    float hf = __uint_as_float(u & 0xffff0000u);
    l = (ushort_t)(__float_as_uint(v - hf) >> 16);
}

// Pack weights into 32x32x16 MFMA B-fragment order, hi/lo bf16.
// frag idx = (t*8 + nt)*64 + lane; elem j: W[t*16 + (lane>>5)*8 + j][nt*32 + (lane&31)]
__device__ __forceinline__ void pack_one(const float* W, int idx,
                                         ushort_t* hi, ushort_t* lo) {
    int l = idx & 63;
    int tn = idx >> 6;
    int nt = tn & 7, t = tn >> 3;
    int k0 = t * 16 + (l >> 5) * 8;
    int col = nt * 32 + (l & 31);
    #pragma unroll
    for (int j = 0; j < 8; ++j) {
        float v = W[(size_t)(k0 + j) * 256 + col];
        ushort_t h, lw;
        split_bf16(v, h, lw);
        hi[(size_t)idx * 8 + j] = h;
        lo[(size_t)idx * 8 + j] = lw;
    }
}

#define FR1 10240    // (320/16)*8*64
#define FR2 8192     // (256/16)*8*64
#define FR3 16384    // (512/16)*8*64
#define PACKB 168    // ceil((FR1+2*FR2+FR3)/256)
#define ZEROB 256    // blocks for the zero path

// blocks [0,PACKB): pack weights; blocks [PACKB, PACKB+ZEROB): zero aggf+counts
__global__ __launch_bounds__(256)
void prep_kernel(const float* __restrict__ mW1, const float* __restrict__ mW2,
                 const float* __restrict__ uW1, const float* __restrict__ uW2,
                 ushort_t* __restrict__ w1hi, ushort_t* __restrict__ w1lo,
                 ushort_t* __restrict__ w2hi, ushort_t* __restrict__ w2lo,
                 ushort_t* __restrict__ u1hi, ushort_t* __restrict__ u1lo,
                 ushort_t* __restrict__ u2hi, ushort_t* __restrict__ u2lo,
                 float4* __restrict__ zp, int n4) {
    if (blockIdx.x >= PACKB) {
        int i = (blockIdx.x - PACKB) * 256 + threadIdx.x;
        int stride = ZEROB * 256;
        float4 z = make_float4(0.f, 0.f, 0.f, 0.f);
        for (; i < n4; i += stride) zp[i] = z;
        return;
    }
    int idx = blockIdx.x * 256 + threadIdx.x;
    if (idx < FR1) { pack_one(mW1, idx, w1hi, w1lo); return; }
    idx -= FR1;
    if (idx < FR2) { pack_one(mW2, idx, w2hi, w2lo); return; }
    idx -= FR2;
    if (idx < FR3) { pack_one(uW1, idx, u1hi, u1lo); return; }
    idx -= FR3;
    if (idx < FR2) { pack_one(uW2, idx, u2hi, u2lo); return; }
}

// ---- counting sort of edges by dst (per batch) ----
__global__ __launch_bounds__(256)
void hist_kernel(const int* __restrict__ eidx, float* __restrict__ counts) {
    int i = blockIdx.x * 256 + threadIdx.x;      // < BSZ*NE
    int b = i >> 16;
    int2 v = ((const int2*)eidx)[i];
    int d = min(max(v.y, 0), NC - 1);
    atomicAdd(&counts[b * NC + d], 1.0f);
}

__global__ __launch_bounds__(1024)
void scan_kernel(const float* __restrict__ counts, int* __restrict__ woff) {
    __shared__ int wsum[16];
    int b = blockIdx.x, t = threadIdx.x;         // 1024 threads, 4 bins each
    int base = b * NC + t * 4;
    int v0 = (int)counts[base],     v1 = (int)counts[base + 1];
    int v2 = (int)counts[base + 2], v3 = (int)counts[base + 3];
    int ts = v0 + v1 + v2 + v3;
    int lane = t & 63;
    int x = ts;
    #pragma unroll
    for (int off = 1; off < 64; off <<= 1) {
        int y = __shfl_up(x, off, 64);
        if (lane >= off) x += y;
    }
    if (lane == 63) wsum[t >> 6] = x;
    __syncthreads();
    if (t == 0) {
        int s = 0;
        #pragma unroll
        for (int w = 0; w < 16; ++w) { int tmp = wsum[w]; wsum[w] = s; s += tmp; }
    }
    __syncthreads();
    int excl = wsum[t >> 6] + (x - ts);
    woff[base]     = excl;
    woff[base + 1] = excl + v0;
    woff[base + 2] = excl + v0 + v1;
    woff[base + 3] = excl + v0 + v1 + v2;
}

__global__ __launch_bounds__(256)
void scatter_kernel(const int* __restrict__ eidx, int* __restrict__ woff,
                    int* __restrict__ sorted) {
    int i = blockIdx.x * 256 + threadIdx.x;      // < BSZ*NE
    int b = i >> 16, e = i & (NE - 1);
    int2 v = ((const int2*)eidx)[i];
    int d = min(max(v.y, 0), NC - 1);
    int pos = atomicAdd(&woff[b * NC + d], 1);
    sorted[(size_t)b * NE + pos] = e;
}

// ======================= P precompute =======================
// Pe = cell_x @ mW1[:256,:] (fp32), Pn = cell_x @ uW1[:256,:] (bf16)
__global__ __launch_bounds__(512, 6)
void pre_kernel(const float* __restrict__ cell_x,
                const ushort_t* __restrict__ w1hi, const ushort_t* __restrict__ w1lo,
                const ushort_t* __restrict__ u1hi, const ushort_t* __restrict__ u1lo,
                float* __restrict__ Pe, ushort_t* __restrict__ Pn) {
    __shared__ ushort_t Us[32 * HPAD];

    const int tid = threadIdx.x;
    const size_t r0 = (size_t)blockIdx.x * 32;     // global row in [0, B*NC)
    const int wv = tid >> 6, ln = tid & 63;
    const int m32 = ln & 31, half = ln >> 5;
    const int col = wv * 32 + m32;

    const ushort_t* wph = w1hi + ((size_t)wv * 64 + ln) * 8;
    const ushort_t* wpl = w1lo + ((size_t)wv * 64 + ln) * 8;
    const ushort_t* uph = u1hi + ((size_t)wv * 64 + ln) * 8;
    const ushort_t* upl = u1lo + ((size_t)wv * 64 + ln) * 8;
    s16x8 wh = *(const s16x8*)wph, wl = *(const s16x8*)wpl;
    s16x8 uh = *(const s16x8*)uph, ul = *(const s16x8*)upl;

    // stage cell_x rows as RNE bf16
    {
        const int row = tid >> 4, c8 = tid & 15;
        const float4* crow = (const float4*)(cell_x + (r0 + row) * HID);
        #pragma unroll
        for (int i = 0; i < 4; ++i) {
            int c = c8 + i * 16;
            float4 v = crow[c];
            *(ushort4*)&Us[row * HPAD + c * 4] =
                make_ushort4(bf16_rne(v.x), bf16_rne(v.y), bf16_rne(v.z), bf16_rne(v.w));
        }
    }
    __syncthreads();

    f32x16 aw, au;
    #pragma unroll
    for (int r = 0; r < 16; ++r) { aw[r] = 0.f; au[r] = 0.f; }

    #pragma unroll 2
    for (int t = 0; t < 16; ++t) {
        int tn = (t + 1 < 16) ? t + 1 : 15;
        s16x8 whn = *(const s16x8*)(wph + (size_t)tn * 4096);
        s16x8 wln = *(const s16x8*)(wpl + (size_t)tn * 4096);
        s16x8 uhn = *(const s16x8*)(uph + (size_t)tn * 4096);
        s16x8 uln = *(const s16x8*)(upl + (size_t)tn * 4096);
        s16x8 a = *(const s16x8*)&Us[m32 * HPAD + t * 16 + half * 8];
        aw = __builtin_amdgcn_mfma_f32_32x32x16_bf16(a, wh, aw, 0, 0, 0);
        aw = __builtin_amdgcn_mfma_f32_32x32x16_bf16(a, wl, aw, 0, 0, 0);
        au = __builtin_amdgcn_mfma_f32_32x32x16_bf16(a, uh, au, 0, 0, 0);
        au = __builtin_amdgcn_mfma_f32_32x32x16_bf16(a, ul, au, 0, 0, 0);
        wh = whn; wl = wln; uh = uhn; ul = uln;
    }

    #pragma unroll
    for (int r = 0; r < 16; ++r) {
        int row = (r & 3) + 8 * (r >> 2) + 4 * half;
        Pe[(r0 + row) * 256 + col] = aw[r];
        Pn[(r0 + row) * 256 + col] = bf16_rne(au[r]);
    }
}

// 64 sorted edges/block, 512 threads = 8 waves; wave wv owns n-tile wv, 2 m-tiles
__global__ __launch_bounds__(512, 4)
void edge_kernel(const float* __restrict__ Pe,
                 const int*   __restrict__ eidx,
                 const int*   __restrict__ sorted,
                 const float* __restrict__ eattr,
                 const ushort_t* __restrict__ w1hi, const ushort_t* __restrict__ w1lo,
                 const float* __restrict__ b1,
                 const ushort_t* __restrict__ w2hi, const ushort_t* __restrict__ w2lo,
                 const float* __restrict__ b2,
                 float* __restrict__ aggf) {
    __shared__ ushort_t Xs[64 * HPAD];   // 33,280 B; staging uses EPAD sub-layout
    __shared__ int s_src[64], s_dst[64], s_eid[64];

    const int tid = threadIdx.x;
    const int b   = blockIdx.x >> 10;            // 1024 blocks per batch
    const int e0  = (blockIdx.x & 1023) * 64;
    const int wv = tid >> 6, ln = tid & 63;
    const int m32 = ln & 31, half = ln >> 5;
    const int col = wv * 32 + m32;

    if (tid < 64) {
        int eid = sorted[(size_t)b * NE + e0 + tid];
        s_eid[tid] = eid;
        int2 v = ((const int2*)eidx)[(size_t)b * NE + eid];
        s_src[tid] = min(max(v.x, 0), NC - 1);
        s_dst[tid] = min(max(v.y, 0), NC - 1);
    }

    // ---- hoisted W1b (eattr-part, packed t=16..19) B-prefetch ----
    const ushort_t* b1ph = w1hi + ((size_t)(16 * 8 + wv) * 64 + ln) * 8;
    const ushort_t* b1pl = w1lo + ((size_t)(16 * 8 + wv) * 64 + ln) * 8;
    s16x8 bh0 = *(const s16x8*)b1ph;
    s16x8 bl0 = *(const s16x8*)b1pl;
    s16x8 bh1 = *(const s16x8*)(b1ph + 4096);
    s16x8 bl1 = *(const s16x8*)(b1pl + 4096);

    __syncthreads();   // barrier 1: s_eid/s_src/s_dst visible

    // ---- issue Pe gather early (32 independent loads, consumed after GEMM1) ----
    float t0[16], t1[16];
    {
        const float* pb = Pe + (size_t)b * NC * 256 + col;
        #pragma unroll
        for (int r = 0; r < 16; ++r) {
            int rw = (r & 3) + 8 * (r >> 2) + 4 * half;
            t0[r] = pb[(size_t)s_src[rw] * 256];
            t1[r] = pb[(size_t)s_src[rw + 32] * 256];
        }
    }

    // ---- stage eattr (64x64, gathered rows) as RNE bf16 ----
    {
        const int row = tid >> 3, c8 = tid & 7;
        const float4* arow = (const float4*)(eattr + ((size_t)b * NE + s_eid[row]) * EF);
        #pragma unroll
        for (int i = 0; i < 2; ++i) {
            int c = c8 + i * 8;                  // float4 index 0..15
            float4 v = arow[c];
            *(ushort4*)&Xs[row * EPAD + c * 4] =
                make_ushort4(bf16_rne(v.x), bf16_rne(v.y), bf16_rne(v.z), bf16_rne(v.w));
        }
    }
    __syncthreads();   // barrier 2: eattr tile ready

    // ---- GEMM1': acc = eattr @ W1b + b1, K=64 ----
    f32x16 A0, A1;
    {
        float bias = b1[col];
        #pragma unroll
        for (int r = 0; r < 16; ++r) { A0[r] = bias; A1[r] = bias; }
    }
    #pragma unroll
    for (int t = 0; t < 4; t += 2) {
        s16x8 nh = *(const s16x8*)(b1ph + (size_t)min(t + 2, 3) * 4096);
        s16x8 nl = *(const s16x8*)(b1pl + (size_t)min(t + 2, 3) * 4096);
        int ao = m32 * EPAD + t * 16 + half * 8;
        s16x8 a0 = *(const s16x8*)&Xs[ao];
        s16x8 a1 = *(const s16x8*)&Xs[ao + 32 * EPAD];
        A0 = __builtin_amdgcn_mfma_f32_32x32x16_bf16(a0, bh0, A0, 0, 0, 0);
        A0 = __builtin_amdgcn_mfma_f32_32x32x16_bf16(a0, bl0, A0, 0, 0, 0);
        A1 = __builtin_amdgcn_mfma_f32_32x32x16_bf16(a1, bh0, A1, 0, 0, 0);
        A1 = __builtin_amdgcn_mfma_f32_32x32x16_bf16(a1, bl0, A1, 0, 0, 0);
        bh0 = nh; bl0 = nl;
        nh = *(const s16x8*)(b1ph + (size_t)min(t + 3, 3) * 4096);
        nl = *(const s16x8*)(b1pl + (size_t)min(t + 3, 3) * 4096);
        ao = m32 * EPAD + (t + 1) * 16 + half * 8;
        a0 = *(const s16x8*)&Xs[ao];
        a1 = *(const s16x8*)&Xs[ao + 32 * EPAD];
        A0 = __builtin_amdgcn_mfma_f32_32x32x16_bf16(a0, bh1, A0, 0, 0, 0);
        A0 = __builtin_amdgcn_mfma_f32_32x32x16_bf16(a0, bl1, A0, 0, 0, 0);
        A1 = __builtin_amdgcn_mfma_f32_32x32x16_bf16(a1, bh1, A1, 0, 0, 0);
        A1 = __builtin_amdgcn_mfma_f32_32x32x16_bf16(a1, bl1, A1, 0, 0, 0);
        bh1 = nh; bl1 = nl;
    }

    // ---- consume gathered Pe[src] ----
    #pragma unroll
    for (int r = 0; r < 16; ++r) { A0[r] += t0[r]; A1[r] += t1[r]; }

    // ---- hoisted W2 B-prefetch ----
    const ushort_t* b2ph = w2hi + ((size_t)wv * 64 + ln) * 8;
    const ushort_t* b2pl = w2lo + ((size_t)wv * 64 + ln) * 8;
    bh0 = *(const s16x8*)b2ph;
    bl0 = *(const s16x8*)b2pl;
    bh1 = *(const s16x8*)(b2ph + 4096);
    bl1 = *(const s16x8*)(b2pl + 4096);

    __syncthreads();   // barrier 3: all eattr reads done; reuse LDS for H

    // ---- relu + RNE bf16 + store hidden (rows = edges) ----
    #pragma unroll
    for (int r = 0; r < 16; ++r) {
        int row = (r & 3) + 8 * (r >> 2) + 4 * half;
        Xs[row * HPAD + col]        = bf16_rne(fmaxf(A0[r], 0.f));
        Xs[(row + 32) * HPAD + col] = bf16_rne(fmaxf(A1[r], 0.f));
    }
    __syncthreads();   // barrier 4: H ready

    // ---- GEMM2: msg = hidden @ W2 + b2, K=256 ----
    f32x16 C0, C1;
    {
        float bias = b2[col];
        #pragma unroll
        for (int r = 0; r < 16; ++r) { C0[r] = bias; C1[r] = bias; }
    }
    for (int t = 0; t < 16; t += 2) {
        s16x8 nh = *(const s16x8*)(b2ph + (size_t)min(t + 2, 15) * 4096);
        s16x8 nl = *(const s16x8*)(b2pl + (size_t)min(t + 2, 15) * 4096);
        int ao = m32 * HPAD + t * 16 + half * 8;
        s16x8 a0 = *(const s16x8*)&Xs[ao];
        s16x8 a1 = *(const s16x8*)&Xs[ao + 32 * HPAD];
        C0 = __builtin_amdgcn_mfma_f32_32x32x16_bf16(a0, bh0, C0, 0, 0, 0);
        C0 = __builtin_amdgcn_mfma_f32_32x32x16_bf16(a0, bl0, C0, 0, 0, 0);
        C1 = __builtin_amdgcn_mfma_f32_32x32x16_bf16(a1, bh0, C1, 0, 0, 0);
        C1 = __builtin_amdgcn_mfma_f32_32x32x16_bf16(a1, bl0, C1, 0, 0, 0);
        bh0 = nh; bl0 = nl;
        nh = *(const s16x8*)(b2ph + (size_t)min(t + 3, 15) * 4096);
        nl = *(const s16x8*)(b2pl + (size_t)min(t + 3, 15) * 4096);
        ao = m32 * HPAD + (t + 1) * 16 + half * 8;
        a0 = *(const s16x8*)&Xs[ao];
        a1 = *(const s16x8*)&Xs[ao + 32 * HPAD];
        C0 = __builtin_amdgcn_mfma_f32_32x32x16_bf16(a0, bh1, C0, 0, 0, 0);
        C0 = __builtin_amdgcn_mfma_f32_32x32x16_bf16(a0, bl1, C0, 0, 0, 0);
        C1 = __builtin_amdgcn_mfma_f32_32x32x16_bf16(a1, bh1, C1, 0, 0, 0);
        C1 = __builtin_amdgcn_mfma_f32_32x32x16_bf16(a1, bl1, C1, 0, 0, 0);
        bh1 = nh; bl1 = nl;
    }

    // ---- in-register segmented reduce over sorted dst runs (fp32, no LDS trip) ----
    // Run boundaries via ballot; per run: predicated reg sum + lane^32 combine +
    // one coalesced fp32 atomic per col from lanes 0..31. All branches wave-uniform.
    {
        const int l31 = ln & 31;
        // C0: block rows 0..31
        int dl = s_dst[l31];
        int dp = (l31 == 0) ? ~dl : s_dst[l31 - 1];
        unsigned m = (unsigned)__ballot(dl != dp);
        unsigned rem = m & ~1u;
        int lo = 0;
        while (lo < 32) {
            int hi = rem ? (int)__builtin_ctz(rem) : 32;
            rem &= rem - 1;
            int d = __shfl(dl, lo, 64);
            float s = 0.f;
            #pragma unroll
            for (int r = 0; r < 16; ++r) {
                int row = (r & 3) + 8 * (r >> 2) + 4 * half;
                s += (row >= lo && row < hi) ? C0[r] : 0.f;
            }
            s += __shfl_xor(s, 32, 64);
            if (ln < 32) atomicAdd(&aggf[((size_t)b * NC + d) * HID + col], s);
            lo = hi;
        }
        // C1: block rows 32..63
        dl = s_dst[32 + l31];
        dp = (l31 == 0) ? ~dl : s_dst[32 + l31 - 1];
        m = (unsigned)__ballot(dl != dp);
        rem = m & ~1u;
        lo = 0;
        while (lo < 32) {
            int hi = rem ? (int)__builtin_ctz(rem) : 32;
            rem &= rem - 1;
            int d = __shfl(dl, lo, 64);
            float s = 0.f;
            #pragma unroll
            for (int r = 0; r < 16; ++r) {
                int row = (r & 3) + 8 * (r >> 2) + 4 * half;
                s += (row >= lo && row < hi) ? C1[r] : 0.f;
            }
            s += __shfl_xor(s, 32, 64);
            if (ln < 32) atomicAdd(&aggf[((size_t)b * NC + d) * HID + col], s);
            lo = hi;
        }
    }
}

// 32 nodes/block, 512 threads = 8 waves; wave wv owns n-tile wv, 1 m-tile
__global__ __launch_bounds__(512, 6)
void node_kernel(const float* __restrict__ cell_x,
                 const float* __restrict__ aggf,
                 const float* __restrict__ counts,
                 const ushort_t* __restrict__ Pn,
                 const ushort_t* __restrict__ u1hi, const ushort_t* __restrict__ u1lo,
                 const float* __restrict__ b1,
                 const ushort_t* __restrict__ u2hi, const ushort_t* __restrict__ u2lo,
                 const float* __restrict__ b2,
                 const float* __restrict__ gamma, const float* __restrict__ beta,
                 float* __restrict__ out) {
    __shared__ ushort_t Us[32 * UPAD];   // pool: agg/H bf16 (32*HPAD) + hs fp32 overlay
    __shared__ float s_inv[32];
    float* hs = (float*)Us;

    const int tid = threadIdx.x;
    const int b   = blockIdx.x >> 7;             // 128 blocks per batch
    const int r0  = (blockIdx.x & 127) * 32;
    const int wv = tid >> 6, ln = tid & 63;
    const int m32 = ln & 31, half = ln >> 5;
    const int col = wv * 32 + m32;

    // hoisted uW1b (agg-part, packed t=16..31) B-prefetch
    const ushort_t* b1ph = u1hi + ((size_t)(16 * 8 + wv) * 64 + ln) * 8;
    const ushort_t* b1pl = u1lo + ((size_t)(16 * 8 + wv) * 64 + ln) * 8;
    s16x8 bhi = *(const s16x8*)b1ph;
    s16x8 blo = *(const s16x8*)b1pl;

    if (tid < 32) {
        float c = counts[b * NC + r0 + tid];
        s_inv[tid] = 1.0f / fmaxf(c, 1.0f);
    }

    // ---- issue Pn gather early (16 loads, consumed after GEMM1) ----
    ushort_t pnt[16];
    {
        const ushort_t* pb = Pn + ((size_t)b * NC + r0) * 256 + col;
        #pragma unroll
        for (int r = 0; r < 16; ++r) {
            int row = (r & 3) + 8 * (r >> 2) + 4 * half;
            pnt[r] = pb[(size_t)row * 256];
        }
    }
    __syncthreads();

    // ---- stage agg*inv (fp32 -> RNE bf16), 32 x 256 ----
    {
        const int row = tid >> 4, c8 = tid & 15;
        const float4* grow = (const float4*)(aggf + ((size_t)b * NC + r0 + row) * HID);
        float inv = s_inv[row];
        #pragma unroll
        for (int i = 0; i < 4; ++i) {
            int c = c8 + i * 16;                 // float4 group index 0..63
            float4 g = grow[c];
            *(ushort4*)&Us[row * HPAD + c * 4] =
                make_ushort4(bf16_rne(g.x * inv), bf16_rne(g.y * inv),
                             bf16_rne(g.z * inv), bf16_rne(g.w * inv));
        }
    }
    __syncthreads();

    // ---- GEMM1': acc = agg @ uW1b + ub1, K=256 ----
    f32x16 acc;
    {
        float bias = b1[col];
        #pragma unroll
        for (int r = 0; r < 16; ++r) acc[r] = bias;
    }
    #pragma unroll 2
    for (int t = 0; t < 16; ++t) {
        int tn1 = (t + 1 < 16) ? t + 1 : 15;
        s16x8 bhin = *(const s16x8*)(b1ph + (size_t)tn1 * 4096);
        s16x8 blon = *(const s16x8*)(b1pl + (size_t)tn1 * 4096);
        s16x8 a = *(const s16x8*)&Us[m32 * HPAD + t * 16 + half * 8];
        acc = __builtin_amdgcn_mfma_f32_32x32x16_bf16(a, bhi, acc, 0, 0, 0);
        acc = __builtin_amdgcn_mfma_f32_32x32x16_bf16(a, blo, acc, 0, 0, 0);
        bhi = bhin; blo = blon;
    }

    // ---- add Pn (cell_x @ uW1a half) ----
    #pragma unroll
    for (int r = 0; r < 16; ++r) acc[r] += bf16_to_f(pnt[r]);

    // hoisted uW2 B-prefetch (before repack barrier)
    const ushort_t* b2ph = u2hi + ((size_t)wv * 64 + ln) * 8;
    const ushort_t* b2pl = u2lo + ((size_t)wv * 64 + ln) * 8;
    bhi = *(const s16x8*)b2ph;
    blo = *(const s16x8*)b2pl;

    __syncthreads();   // agg tile dead; reuse for H

    #pragma unroll
    for (int r = 0; r < 16; ++r) {
        int row = (r & 3) + 8 * (r >> 2) + 4 * half;
        Us[row * HPAD + col] = bf16_rne(fmaxf(acc[r], 0.f));
    }
    __syncthreads();

    // ---- issue residual cell_x loads early (consumed after GEMM2) ----
    float cxt[16];
    #pragma unroll
    for (int r = 0; r < 16; ++r) {
        int row = (r & 3) + 8 * (r >> 2) + 4 * half;
        cxt[r] = cell_x[((size_t)b * NC + r0 + row) * HID + col];
    }

    // ---- GEMM2: o = hidden @ uW2 + ub2, K=256 ----
    f32x16 c2;
    {
        float bias = b2[col];
        #pragma unroll
        for (int r = 0; r < 16; ++r) c2[r] = bias;
    }
    #pragma unroll 2
    for (int t = 0; t < 16; ++t) {
        int tn1 = (t + 1 < 16) ? t + 1 : 15;
        s16x8 bhin = *(const s16x8*)(b2ph + (size_t)tn1 * 4096);
        s16x8 blon = *(const s16x8*)(b2pl + (size_t)tn1 * 4096);
        s16x8 a = *(const s16x8*)&Us[m32 * HPAD + t * 16 + half * 8];
        c2 = __builtin_amdgcn_mfma_f32_32x32x16_bf16(a, bhi, c2, 0, 0, 0);
        c2 = __builtin_amdgcn_mfma_f32_32x32x16_bf16(a, blo, c2, 0, 0, 0);
        bhi = bhin; blo = blon;
    }
    __syncthreads();   // H dead; reuse pool for hs (fp32)

    // ---- residual: h = cell_x + o ----
    #pragma unroll
    for (int r = 0; r < 16; ++r) {
        int row = (r & 3) + 8 * (r >> 2) + 4 * half;
        hs[row * HSF + col] = c2[r] + cxt[r];
    }
    __syncthreads();

    // ---- LayerNorm per row: wave wv handles rows wv*4..+3 ----
    #pragma unroll
    for (int i = 0; i < 4; ++i) {
        int r = wv * 4 + i;
        float v[4];
        float s = 0.f, q = 0.f;
        #pragma unroll
        for (int j = 0; j < 4; ++j) {
            v[j] = hs[r * HSF + ln + 64 * j];
            s += v[j];
            q = fmaf(v[j], v[j], q);
        }
        #pragma unroll
        for (int off = 32; off > 0; off >>= 1) {
            s += __shfl_xor(s, off, 64);
            q += __shfl_xor(q, off, 64);
        }
        float mu = s * (1.0f / HID);
        float var = q * (1.0f / HID) - mu * mu;
        float rs = rsqrtf(var + EPSV);
        float* orow = out + ((size_t)b * NC + r0 + r) * HID;
        #pragma unroll
        for (int j = 0; j < 4; ++j) {
            int c = ln + 64 * j;
            orow[c] = (v[j] - mu) * rs * gamma[c] + beta[c];
        }
    }
}

extern "C" void kernel_launch(void* const* d_in, const int* in_sizes, int n_in,
                              void* d_out, int out_size, void* d_ws, size_t ws_size,
                              hipStream_t stream) {
    const float* cell_x = (const float*)d_in[0];
    const int*   eidx   = (const int*)d_in[1];
    const float* eattr  = (const float*)d_in[2];
    const float* mW1    = (const float*)d_in[3];
    const float* mb1    = (const float*)d_in[4];
    const float* mW2    = (const float*)d_in[5];
    const float* mb2    = (const float*)d_in[6];
    const float* uW1    = (const float*)d_in[7];
    const float* ub1    = (const float*)d_in[8];
    const float* uW2    = (const float*)d_in[9];
    const float* ub2    = (const float*)d_in[10];
    const float* gamma  = (const float*)d_in[11];
    const float* beta   = (const float*)d_in[12];
    float* out = (float*)d_out;

    // workspace layout (~41.8 MB; harness proven >= 43.35 MB)
    float* aggf   = (float*)d_ws;                        // [B,NC,HID] fp32, 16 MB
    float* counts = aggf + (size_t)BSZ * NC * HID;       // [B,NC] fp32, 64 KB
    int*   woff   = (int*)(counts + BSZ * NC);           // [B,NC] int, 64 KB
    int*   sorted = woff + BSZ * NC;                     // [B,NE] int, 1 MB
    ushort_t* w1hi = (ushort_t*)(sorted + (size_t)BSZ * NE);
    ushort_t* w1lo = w1hi + KIN * HID;
    ushort_t* w2hi = w1lo + KIN * HID;
    ushort_t* w2lo = w2hi + HID * HID;
    ushort_t* u1hi = w2lo + HID * HID;
    ushort_t* u1lo = u1hi + 2 * HID * HID;
    ushort_t* u2hi = u1lo + 2 * HID * HID;
    ushort_t* u2lo = u2hi + HID * HID;
    float*    Pe   = (float*)(u2lo + HID * HID);         // [B*NC,256] fp32, 16 MB
    ushort_t* Pn   = (ushort_t*)(Pe + (size_t)BSZ * NC * 256); // [B*NC,256] bf16, 8 MB

    // zero aggf + counts (contiguous): bytes = B*NC*HID*4 + B*NC*4
    int n4 = (BSZ * NC * HID * 4 + BSZ * NC * 4) / 16;
    prep_kernel<<<PACKB + ZEROB, 256, 0, stream>>>(
        mW1, mW2, uW1, uW2, w1hi, w1lo, w2hi, w2lo, u1hi, u1lo, u2hi, u2lo,
        (float4*)d_ws, n4);
    hist_kernel<<<BSZ * NE / 256, 256, 0, stream>>>(eidx, counts);
    scan_kernel<<<BSZ, 1024, 0, stream>>>(counts, woff);
    scatter_kernel<<<BSZ * NE / 256, 256, 0, stream>>>(eidx, woff, sorted);
    pre_kernel<<<BSZ * NC / 32, 512, 0, stream>>>(cell_x, w1hi, w1lo, u1hi, u1lo, Pe, Pn);
    edge_kernel<<<BSZ * NE / 64, 512, 0, stream>>>(Pe, eidx, sorted, eattr,
                                                   w1hi, w1lo, mb1, w2hi, w2lo, mb2,
                                                   aggf);
    node_kernel<<<BSZ * NC / 32, 512, 0, stream>>>(cell_x, aggf, counts, Pn,
                                                   u1hi, u1lo, ub1, u2hi, u2lo, ub2,
                                                   gamma, beta, out);
}

// Round 5
// 271.803 us; speedup vs baseline: 1.2767x; 1.1330x over previous
//
#include <hip/hip_runtime.h>

#define HID 256
#define EF  64
#define KIN 320      // HID + EF
#define NC  4096
#define NE  65536
#define BSZ 4
#define EPSV 1e-5f

typedef unsigned short ushort_t;
typedef __attribute__((ext_vector_type(8))) short s16x8;
typedef __attribute__((ext_vector_type(16))) float f32x16;

// LDS strides in ushort elements (stride mod 32 words == 2 -> free 2-way alias)
#define EPAD 68      // edge-attr tile row: 136 B
#define HPAD 260     // hidden tile row: 520 B
#define UPAD 520     // node LDS pool row: 1040 B
#define HSF  260     // node h (fp32) stride

// round-to-nearest-even fp32 -> bf16 (as ushort bits)
__device__ __forceinline__ ushort_t bf16_rne(float f) {
    unsigned u = __float_as_uint(f);
    return (ushort_t)((u + 0x7fffu + ((u >> 16) & 1u)) >> 16);
}
__device__ __forceinline__ float bf16_to_f(ushort_t u) {
    return __uint_as_float(((unsigned)u) << 16);
}
// truncating hi/lo split (pair sums to ~fp32 precision) — for weights (B operand)
__device__ __forceinline__ void split_bf16(float v, ushort_t& h, ushort_t& l) {
    unsigned u = __float_as_uint(v);
    h = (ushort_t)(u >> 16);
    float hf = __uint_as_float(u & 0xffff0000u);
    l = (ushort_t)(__float_as_uint(v - hf) >> 16);
}

// Pack weights into 32x32x16 MFMA B-fragment order, hi/lo bf16.
// frag idx = (t*8 + nt)*64 + lane; elem j: W[t*16 + (lane>>5)*8 + j][nt*32 + (lane&31)]
__device__ __forceinline__ void pack_one(const float* W, int idx,
                                         ushort_t* hi, ushort_t* lo) {
    int l = idx & 63;
    int tn = idx >> 6;
    int nt = tn & 7, t = tn >> 3;
    int k0 = t * 16 + (l >> 5) * 8;
    int col = nt * 32 + (l & 31);
    #pragma unroll
    for (int j = 0; j < 8; ++j) {
        float v = W[(size_t)(k0 + j) * 256 + col];
        ushort_t h, lw;
        split_bf16(v, h, lw);
        hi[(size_t)idx * 8 + j] = h;
        lo[(size_t)idx * 8 + j] = lw;
    }
}

#define FR1 10240    // (320/16)*8*64   mW1 full
#define FR2 8192     // (256/16)*8*64   one 256x256
#define PACK1B 104   // (FR1 + 2*FR2)/256 : mW1, uW1a, uW2
#define FUSEB 256    // W2u rows
#define ZEROB 256

// prep: blocks [0,104) pack mW1/uW1a/uW2; [104,360) fuse W2u = mW2 @ uW1b;
// [360] bias2u = mb2 @ uW1b + ub1; [361,617) zero aggf+counts
__global__ __launch_bounds__(256)
void prep_kernel(const float* __restrict__ mW1, const float* __restrict__ uW1,
                 const float* __restrict__ uW2, const float* __restrict__ mW2,
                 const float* __restrict__ ub1, const float* __restrict__ mb2,
                 ushort_t* __restrict__ w1hi, ushort_t* __restrict__ w1lo,
                 ushort_t* __restrict__ u1hi, ushort_t* __restrict__ u1lo,
                 ushort_t* __restrict__ u2hi, ushort_t* __restrict__ u2lo,
                 float* __restrict__ W2u, float* __restrict__ bias2u,
                 float4* __restrict__ zp, int n4) {
    int bid = blockIdx.x;
    if (bid < PACK1B) {
        int idx = bid * 256 + threadIdx.x;
        if (idx < FR1) { pack_one(mW1, idx, w1hi, w1lo); return; }
        idx -= FR1;
        if (idx < FR2) { pack_one(uW1, idx, u1hi, u1lo); return; }
        idx -= FR2;
        pack_one(uW2, idx, u2hi, u2lo);
        return;
    }
    bid -= PACK1B;
    if (bid < FUSEB) {               // W2u[k][n] = sum_m mW2[k][m] * uW1[256+m][n]
        int k = bid, n = threadIdx.x;
        const float* wrow = mW2 + (size_t)k * 256;
        float acc = 0.f;
        #pragma unroll 8
        for (int m = 0; m < 256; ++m)
            acc = fmaf(wrow[m], uW1[(size_t)(256 + m) * 256 + n], acc);
        W2u[(size_t)k * 256 + n] = acc;
        return;
    }
    bid -= FUSEB;
    if (bid == 0) {                  // bias2u[n] = ub1[n] + sum_m mb2[m]*uW1[256+m][n]
        int n = threadIdx.x;
        float acc = ub1[n];
        #pragma unroll 8
        for (int m = 0; m < 256; ++m)
            acc = fmaf(mb2[m], uW1[(size_t)(256 + m) * 256 + n], acc);
        bias2u[n] = acc;
        return;
    }
    bid -= 1;
    int i = bid * 256 + threadIdx.x;
    int stride = ZEROB * 256;
    float4 z = make_float4(0.f, 0.f, 0.f, 0.f);
    for (; i < n4; i += stride) zp[i] = z;
}

// ---- counting sort of edges by dst (per batch) ----
__global__ __launch_bounds__(256)
void hist_kernel(const int* __restrict__ eidx, float* __restrict__ counts) {
    int i = blockIdx.x * 256 + threadIdx.x;      // < BSZ*NE
    int b = i >> 16;
    int2 v = ((const int2*)eidx)[i];
    int d = min(max(v.y, 0), NC - 1);
    atomicAdd(&counts[b * NC + d], 1.0f);
}

// blocks [0,BSZ): scan; blocks [BSZ, BSZ+32): pack W2u fragments
__global__ __launch_bounds__(1024)
void scan_kernel(const float* __restrict__ counts, int* __restrict__ woff,
                 const float* __restrict__ W2u,
                 ushort_t* __restrict__ w2uhi, ushort_t* __restrict__ w2ulo) {
    if (blockIdx.x >= BSZ) {
        if (threadIdx.x < 256) {
            int idx = (blockIdx.x - BSZ) * 256 + threadIdx.x;   // < FR2
            pack_one(W2u, idx, w2uhi, w2ulo);
        }
        return;
    }
    __shared__ int wsum[16];
    int b = blockIdx.x, t = threadIdx.x;         // 1024 threads, 4 bins each
    int base = b * NC + t * 4;
    int v0 = (int)counts[base],     v1 = (int)counts[base + 1];
    int v2 = (int)counts[base + 2], v3 = (int)counts[base + 3];
    int ts = v0 + v1 + v2 + v3;
    int lane = t & 63;
    int x = ts;
    #pragma unroll
    for (int off = 1; off < 64; off <<= 1) {
        int y = __shfl_up(x, off, 64);
        if (lane >= off) x += y;
    }
    if (lane == 63) wsum[t >> 6] = x;
    __syncthreads();
    if (t == 0) {
        int s = 0;
        #pragma unroll
        for (int w = 0; w < 16; ++w) { int tmp = wsum[w]; wsum[w] = s; s += tmp; }
    }
    __syncthreads();
    int excl = wsum[t >> 6] + (x - ts);
    woff[base]     = excl;
    woff[base + 1] = excl + v0;
    woff[base + 2] = excl + v0 + v1;
    woff[base + 3] = excl + v0 + v1 + v2;
}

__global__ __launch_bounds__(256)
void scatter_kernel(const int* __restrict__ eidx, int* __restrict__ woff,
                    int* __restrict__ sorted) {
    int i = blockIdx.x * 256 + threadIdx.x;      // < BSZ*NE
    int b = i >> 16, e = i & (NE - 1);
    int2 v = ((const int2*)eidx)[i];
    int d = min(max(v.y, 0), NC - 1);
    int pos = atomicAdd(&woff[b * NC + d], 1);
    sorted[(size_t)b * NE + pos] = e;
}

// ======================= P precompute =======================
// Pe = cell_x @ mW1[:256,:] (fp32), Pn = cell_x @ uW1[:256,:] (bf16)
__global__ __launch_bounds__(512, 6)
void pre_kernel(const float* __restrict__ cell_x,
                const ushort_t* __restrict__ w1hi, const ushort_t* __restrict__ w1lo,
                const ushort_t* __restrict__ u1hi, const ushort_t* __restrict__ u1lo,
                float* __restrict__ Pe, ushort_t* __restrict__ Pn) {
    __shared__ ushort_t Us[32 * HPAD];

    const int tid = threadIdx.x;
    const size_t r0 = (size_t)blockIdx.x * 32;     // global row in [0, B*NC)
    const int wv = tid >> 6, ln = tid & 63;
    const int m32 = ln & 31, half = ln >> 5;
    const int col = wv * 32 + m32;

    const ushort_t* wph = w1hi + ((size_t)wv * 64 + ln) * 8;
    const ushort_t* wpl = w1lo + ((size_t)wv * 64 + ln) * 8;
    const ushort_t* uph = u1hi + ((size_t)wv * 64 + ln) * 8;
    const ushort_t* upl = u1lo + ((size_t)wv * 64 + ln) * 8;
    s16x8 wh = *(const s16x8*)wph, wl = *(const s16x8*)wpl;
    s16x8 uh = *(const s16x8*)uph, ul = *(const s16x8*)upl;

    // stage cell_x rows as RNE bf16
    {
        const int row = tid >> 4, c8 = tid & 15;
        const float4* crow = (const float4*)(cell_x + (r0 + row) * HID);
        #pragma unroll
        for (int i = 0; i < 4; ++i) {
            int c = c8 + i * 16;
            float4 v = crow[c];
            *(ushort4*)&Us[row * HPAD + c * 4] =
                make_ushort4(bf16_rne(v.x), bf16_rne(v.y), bf16_rne(v.z), bf16_rne(v.w));
        }
    }
    __syncthreads();

    f32x16 aw, au;
    #pragma unroll
    for (int r = 0; r < 16; ++r) { aw[r] = 0.f; au[r] = 0.f; }

    #pragma unroll 2
    for (int t = 0; t < 16; ++t) {
        int tn = (t + 1 < 16) ? t + 1 : 15;
        s16x8 whn = *(const s16x8*)(wph + (size_t)tn * 4096);
        s16x8 wln = *(const s16x8*)(wpl + (size_t)tn * 4096);
        s16x8 uhn = *(const s16x8*)(uph + (size_t)tn * 4096);
        s16x8 uln = *(const s16x8*)(upl + (size_t)tn * 4096);
        s16x8 a = *(const s16x8*)&Us[m32 * HPAD + t * 16 + half * 8];
        aw = __builtin_amdgcn_mfma_f32_32x32x16_bf16(a, wh, aw, 0, 0, 0);
        aw = __builtin_amdgcn_mfma_f32_32x32x16_bf16(a, wl, aw, 0, 0, 0);
        au = __builtin_amdgcn_mfma_f32_32x32x16_bf16(a, uh, au, 0, 0, 0);
        au = __builtin_amdgcn_mfma_f32_32x32x16_bf16(a, ul, au, 0, 0, 0);
        wh = whn; wl = wln; uh = uhn; ul = uln;
    }

    #pragma unroll
    for (int r = 0; r < 16; ++r) {
        int row = (r & 3) + 8 * (r >> 2) + 4 * half;
        Pe[(r0 + row) * 256 + col] = aw[r];
        Pn[(r0 + row) * 256 + col] = bf16_rne(au[r]);
    }
}

// 64 sorted edges/block, 512 threads = 8 waves.
// Computes relu(X@mW1+mb1) only (GEMM2 folded into node via W2u), then
// segment-reduces relu-H over sorted dst runs into aggf (fp32 atomics).
__global__ __launch_bounds__(512, 4)
void edge_kernel(const float* __restrict__ Pe,
                 const int*   __restrict__ eidx,
                 const int*   __restrict__ sorted,
                 const float* __restrict__ eattr,
                 const ushort_t* __restrict__ w1hi, const ushort_t* __restrict__ w1lo,
                 const float* __restrict__ b1,
                 float* __restrict__ aggf) {
    __shared__ ushort_t Xs[64 * EPAD];   // 8,704 B
    __shared__ int s_src[64], s_dst[64], s_eid[64];

    const int tid = threadIdx.x;
    const int b   = blockIdx.x >> 10;            // 1024 blocks per batch
    const int e0  = (blockIdx.x & 1023) * 64;
    const int wv = tid >> 6, ln = tid & 63;
    const int m32 = ln & 31, half = ln >> 5;
    const int col = wv * 32 + m32;

    if (tid < 64) {
        int eid = sorted[(size_t)b * NE + e0 + tid];
        s_eid[tid] = eid;
        int2 v = ((const int2*)eidx)[(size_t)b * NE + eid];
        s_src[tid] = min(max(v.x, 0), NC - 1);
        s_dst[tid] = min(max(v.y, 0), NC - 1);
    }

    // ---- W1b (eattr part, packed t=16..19) B fragments, all upfront ----
    const ushort_t* ph = w1hi + ((size_t)(16 * 8 + wv) * 64 + ln) * 8;
    const ushort_t* pl = w1lo + ((size_t)(16 * 8 + wv) * 64 + ln) * 8;
    s16x8 bh0 = *(const s16x8*)ph;
    s16x8 bl0 = *(const s16x8*)pl;
    s16x8 bh1 = *(const s16x8*)(ph + 4096);
    s16x8 bl1 = *(const s16x8*)(pl + 4096);
    s16x8 bh2 = *(const s16x8*)(ph + 8192);
    s16x8 bl2 = *(const s16x8*)(pl + 8192);
    s16x8 bh3 = *(const s16x8*)(ph + 12288);
    s16x8 bl3 = *(const s16x8*)(pl + 12288);

    __syncthreads();   // ids visible

    // ---- issue Pe gather early (32 independent loads) ----
    float t0[16], t1[16];
    {
        const float* pb = Pe + (size_t)b * NC * 256 + col;
        #pragma unroll
        for (int r = 0; r < 16; ++r) {
            int rw = (r & 3) + 8 * (r >> 2) + 4 * half;
            t0[r] = pb[(size_t)s_src[rw] * 256];
            t1[r] = pb[(size_t)s_src[rw + 32] * 256];
        }
    }

    // ---- stage eattr (64x64, gathered rows) as RNE bf16 ----
    {
        const int row = tid >> 3, c8 = tid & 7;
        const float4* arow = (const float4*)(eattr + ((size_t)b * NE + s_eid[row]) * EF);
        #pragma unroll
        for (int i = 0; i < 2; ++i) {
            int c = c8 + i * 8;
            float4 v = arow[c];
            *(ushort4*)&Xs[row * EPAD + c * 4] =
                make_ushort4(bf16_rne(v.x), bf16_rne(v.y), bf16_rne(v.z), bf16_rne(v.w));
        }
    }
    __syncthreads();   // eattr tile ready

    // ---- GEMM1: h1 = eattr @ W1b + b1 (Pe added after), K=64 ----
    f32x16 A0, A1;
    {
        float bias = b1[col];
        #pragma unroll
        for (int r = 0; r < 16; ++r) { A0[r] = bias; A1[r] = bias; }
    }
    {
        int ao = m32 * EPAD + half * 8;
        s16x8 a0, a1;
        a0 = *(const s16x8*)&Xs[ao];      a1 = *(const s16x8*)&Xs[ao + 32 * EPAD];
        A0 = __builtin_amdgcn_mfma_f32_32x32x16_bf16(a0, bh0, A0, 0, 0, 0);
        A0 = __builtin_amdgcn_mfma_f32_32x32x16_bf16(a0, bl0, A0, 0, 0, 0);
        A1 = __builtin_amdgcn_mfma_f32_32x32x16_bf16(a1, bh0, A1, 0, 0, 0);
        A1 = __builtin_amdgcn_mfma_f32_32x32x16_bf16(a1, bl0, A1, 0, 0, 0);
        a0 = *(const s16x8*)&Xs[ao + 16]; a1 = *(const s16x8*)&Xs[ao + 16 + 32 * EPAD];
        A0 = __builtin_amdgcn_mfma_f32_32x32x16_bf16(a0, bh1, A0, 0, 0, 0);
        A0 = __builtin_amdgcn_mfma_f32_32x32x16_bf16(a0, bl1, A0, 0, 0, 0);
        A1 = __builtin_amdgcn_mfma_f32_32x32x16_bf16(a1, bh1, A1, 0, 0, 0);
        A1 = __builtin_amdgcn_mfma_f32_32x32x16_bf16(a1, bl1, A1, 0, 0, 0);
        a0 = *(const s16x8*)&Xs[ao + 32]; a1 = *(const s16x8*)&Xs[ao + 32 + 32 * EPAD];
        A0 = __builtin_amdgcn_mfma_f32_32x32x16_bf16(a0, bh2, A0, 0, 0, 0);
        A0 = __builtin_amdgcn_mfma_f32_32x32x16_bf16(a0, bl2, A0, 0, 0, 0);
        A1 = __builtin_amdgcn_mfma_f32_32x32x16_bf16(a1, bh2, A1, 0, 0, 0);
        A1 = __builtin_amdgcn_mfma_f32_32x32x16_bf16(a1, bl2, A1, 0, 0, 0);
        a0 = *(const s16x8*)&Xs[ao + 48]; a1 = *(const s16x8*)&Xs[ao + 48 + 32 * EPAD];
        A0 = __builtin_amdgcn_mfma_f32_32x32x16_bf16(a0, bh3, A0, 0, 0, 0);
        A0 = __builtin_amdgcn_mfma_f32_32x32x16_bf16(a0, bl3, A0, 0, 0, 0);
        A1 = __builtin_amdgcn_mfma_f32_32x32x16_bf16(a1, bh3, A1, 0, 0, 0);
        A1 = __builtin_amdgcn_mfma_f32_32x32x16_bf16(a1, bl3, A1, 0, 0, 0);
    }

    // ---- fold Pe[src] + relu ----
    #pragma unroll
    for (int r = 0; r < 16; ++r) {
        A0[r] = fmaxf(A0[r] + t0[r], 0.f);
        A1[r] = fmaxf(A1[r] + t1[r], 0.f);
    }

    // ---- in-register segmented reduce over sorted dst runs (fp32 atomics) ----
    {
        const int l31 = ln & 31;
        // rows 0..31 (A0)
        int dl = s_dst[l31];
        int dp = (l31 == 0) ? ~dl : s_dst[l31 - 1];
        unsigned m = (unsigned)__ballot(dl != dp);
        unsigned rem = m & ~1u;
        int lo = 0;
        while (lo < 32) {
            int hi = rem ? (int)__builtin_ctz(rem) : 32;
            rem &= rem - 1;
            int d = __shfl(dl, lo, 64);
            float s = 0.f;
            #pragma unroll
            for (int r = 0; r < 16; ++r) {
                int row = (r & 3) + 8 * (r >> 2) + 4 * half;
                s += (row >= lo && row < hi) ? A0[r] : 0.f;
            }
            s += __shfl_xor(s, 32, 64);
            if (ln < 32) atomicAdd(&aggf[((size_t)b * NC + d) * HID + col], s);
            lo = hi;
        }
        // rows 32..63 (A1)
        dl = s_dst[32 + l31];
        dp = (l31 == 0) ? ~dl : s_dst[32 + l31 - 1];
        m = (unsigned)__ballot(dl != dp);
        rem = m & ~1u;
        lo = 0;
        while (lo < 32) {
            int hi = rem ? (int)__builtin_ctz(rem) : 32;
            rem &= rem - 1;
            int d = __shfl(dl, lo, 64);
            float s = 0.f;
            #pragma unroll
            for (int r = 0; r < 16; ++r) {
                int row = (r & 3) + 8 * (r >> 2) + 4 * half;
                s += (row >= lo && row < hi) ? A1[r] : 0.f;
            }
            s += __shfl_xor(s, 32, 64);
            if (ln < 32) atomicAdd(&aggf[((size_t)b * NC + d) * HID + col], s);
            lo = hi;
        }
    }
}

// 32 nodes/block, 512 threads = 8 waves; wave wv owns n-tile wv, 1 m-tile
__global__ __launch_bounds__(512, 6)
void node_kernel(const float* __restrict__ cell_x,
                 const float* __restrict__ aggf,
                 const float* __restrict__ counts,
                 const ushort_t* __restrict__ Pn,
                 const ushort_t* __restrict__ w2uhi, const ushort_t* __restrict__ w2ulo,
                 const float* __restrict__ bias2u,
                 const ushort_t* __restrict__ u2hi, const ushort_t* __restrict__ u2lo,
                 const float* __restrict__ b2,
                 const float* __restrict__ gamma, const float* __restrict__ beta,
                 float* __restrict__ out) {
    __shared__ ushort_t Us[32 * UPAD];   // pool: aggH/H bf16 (32*HPAD) + hs fp32 overlay
    __shared__ float s_inv[32];
    float* hs = (float*)Us;

    const int tid = threadIdx.x;
    const int b   = blockIdx.x >> 7;             // 128 blocks per batch
    const int r0  = (blockIdx.x & 127) * 32;
    const int wv = tid >> 6, ln = tid & 63;
    const int m32 = ln & 31, half = ln >> 5;
    const int col = wv * 32 + m32;

    // hoisted W2u (fused mW2@uW1b) B-prefetch
    const ushort_t* b1ph = w2uhi + ((size_t)wv * 64 + ln) * 8;
    const ushort_t* b1pl = w2ulo + ((size_t)wv * 64 + ln) * 8;
    s16x8 bhi = *(const s16x8*)b1ph;
    s16x8 blo = *(const s16x8*)b1pl;

    if (tid < 32) {
        float c = counts[b * NC + r0 + tid];
        s_inv[tid] = 1.0f / fmaxf(c, 1.0f);
    }

    // ---- issue Pn gather early (consumed after GEMM1) ----
    ushort_t pnt[16];
    {
        const ushort_t* pb = Pn + ((size_t)b * NC + r0) * 256 + col;
        #pragma unroll
        for (int r = 0; r < 16; ++r) {
            int row = (r & 3) + 8 * (r >> 2) + 4 * half;
            pnt[r] = pb[(size_t)row * 256];
        }
    }
    __syncthreads();

    // ---- stage aggH*inv (fp32 -> RNE bf16), 32 x 256 ----
    {
        const int row = tid >> 4, c8 = tid & 15;
        const float4* grow = (const float4*)(aggf + ((size_t)b * NC + r0 + row) * HID);
        float inv = s_inv[row];
        #pragma unroll
        for (int i = 0; i < 4; ++i) {
            int c = c8 + i * 16;
            float4 g = grow[c];
            *(ushort4*)&Us[row * HPAD + c * 4] =
                make_ushort4(bf16_rne(g.x * inv), bf16_rne(g.y * inv),
                             bf16_rne(g.z * inv), bf16_rne(g.w * inv));
        }
    }
    __syncthreads();

    // ---- GEMM1: acc = (aggH/deg) @ W2u + bias2u, K=256 ----
    f32x16 acc;
    {
        float bias = bias2u[col];
        #pragma unroll
        for (int r = 0; r < 16; ++r) acc[r] = bias;
    }
    #pragma unroll 2
    for (int t = 0; t < 16; ++t) {
        int tn1 = (t + 1 < 16) ? t + 1 : 15;
        s16x8 bhin = *(const s16x8*)(b1ph + (size_t)tn1 * 4096);
        s16x8 blon = *(const s16x8*)(b1pl + (size_t)tn1 * 4096);
        s16x8 a = *(const s16x8*)&Us[m32 * HPAD + t * 16 + half * 8];
        acc = __builtin_amdgcn_mfma_f32_32x32x16_bf16(a, bhi, acc, 0, 0, 0);
        acc = __builtin_amdgcn_mfma_f32_32x32x16_bf16(a, blo, acc, 0, 0, 0);
        bhi = bhin; blo = blon;
    }

    // ---- add Pn (cell_x @ uW1a half) ----
    #pragma unroll
    for (int r = 0; r < 16; ++r) acc[r] += bf16_to_f(pnt[r]);

    // hoisted uW2 B-prefetch (before repack barrier)
    const ushort_t* b2ph = u2hi + ((size_t)wv * 64 + ln) * 8;
    const ushort_t* b2pl = u2lo + ((size_t)wv * 64 + ln) * 8;
    bhi = *(const s16x8*)b2ph;
    blo = *(const s16x8*)b2pl;

    __syncthreads();   // agg tile dead; reuse for H

    #pragma unroll
    for (int r = 0; r < 16; ++r) {
        int row = (r & 3) + 8 * (r >> 2) + 4 * half;
        Us[row * HPAD + col] = bf16_rne(fmaxf(acc[r], 0.f));
    }
    __syncthreads();

    // ---- issue residual cell_x loads early (consumed after GEMM2) ----
    float cxt[16];
    #pragma unroll
    for (int r = 0; r < 16; ++r) {
        int row = (r & 3) + 8 * (r >> 2) + 4 * half;
        cxt[r] = cell_x[((size_t)b * NC + r0 + row) * HID + col];
    }

    // ---- GEMM2: o = hidden @ uW2 + ub2, K=256 ----
    f32x16 c2;
    {
        float bias = b2[col];
        #pragma unroll
        for (int r = 0; r < 16; ++r) c2[r] = bias;
    }
    #pragma unroll 2
    for (int t = 0; t < 16; ++t) {
        int tn1 = (t + 1 < 16) ? t + 1 : 15;
        s16x8 bhin = *(const s16x8*)(b2ph + (size_t)tn1 * 4096);
        s16x8 blon = *(const s16x8*)(b2pl + (size_t)tn1 * 4096);
        s16x8 a = *(const s16x8*)&Us[m32 * HPAD + t * 16 + half * 8];
        c2 = __builtin_amdgcn_mfma_f32_32x32x16_bf16(a, bhi, c2, 0, 0, 0);
        c2 = __builtin_amdgcn_mfma_f32_32x32x16_bf16(a, blo, c2, 0, 0, 0);
        bhi = bhin; blo = blon;
    }
    __syncthreads();   // H dead; reuse pool for hs (fp32)

    // ---- residual: h = cell_x + o ----
    #pragma unroll
    for (int r = 0; r < 16; ++r) {
        int row = (r & 3) + 8 * (r >> 2) + 4 * half;
        hs[row * HSF + col] = c2[r] + cxt[r];
    }
    __syncthreads();

    // ---- LayerNorm per row: wave wv handles rows wv*4..+3 ----
    #pragma unroll
    for (int i = 0; i < 4; ++i) {
        int r = wv * 4 + i;
        float v[4];
        float s = 0.f, q = 0.f;
        #pragma unroll
        for (int j = 0; j < 4; ++j) {
            v[j] = hs[r * HSF + ln + 64 * j];
            s += v[j];
            q = fmaf(v[j], v[j], q);
        }
        #pragma unroll
        for (int off = 32; off > 0; off >>= 1) {
            s += __shfl_xor(s, off, 64);
            q += __shfl_xor(q, off, 64);
        }
        float mu = s * (1.0f / HID);
        float var = q * (1.0f / HID) - mu * mu;
        float rs = rsqrtf(var + EPSV);
        float* orow = out + ((size_t)b * NC + r0 + r) * HID;
        #pragma unroll
        for (int j = 0; j < 4; ++j) {
            int c = ln + 64 * j;
            orow[c] = (v[j] - mu) * rs * gamma[c] + beta[c];
        }
    }
}

extern "C" void kernel_launch(void* const* d_in, const int* in_sizes, int n_in,
                              void* d_out, int out_size, void* d_ws, size_t ws_size,
                              hipStream_t stream) {
    const float* cell_x = (const float*)d_in[0];
    const int*   eidx   = (const int*)d_in[1];
    const float* eattr  = (const float*)d_in[2];
    const float* mW1    = (const float*)d_in[3];
    const float* mb1    = (const float*)d_in[4];
    const float* mW2    = (const float*)d_in[5];
    const float* mb2    = (const float*)d_in[6];
    const float* uW1    = (const float*)d_in[7];
    const float* ub1    = (const float*)d_in[8];
    const float* uW2    = (const float*)d_in[9];
    const float* ub2    = (const float*)d_in[10];
    const float* gamma  = (const float*)d_in[11];
    const float* beta   = (const float*)d_in[12];
    float* out = (float*)d_out;

    // workspace layout (~42.44 MB; round-4's 42.44 MB layout passed)
    float* aggf   = (float*)d_ws;                        // [B,NC,HID] fp32, 16 MB
    float* counts = aggf + (size_t)BSZ * NC * HID;       // [B,NC] fp32
    int*   woff   = (int*)(counts + BSZ * NC);           // [B,NC] int
    int*   sorted = woff + BSZ * NC;                     // [B,NE] int, 1 MB
    ushort_t* w1hi = (ushort_t*)(sorted + (size_t)BSZ * NE);   // mW1 pack (320 rows)
    ushort_t* w1lo = w1hi + KIN * HID;
    ushort_t* u1hi = w1lo + KIN * HID;                   // uW1[:256] pack
    ushort_t* u1lo = u1hi + HID * HID;
    ushort_t* u2hi = u1lo + HID * HID;                   // uW2 pack
    ushort_t* u2lo = u2hi + HID * HID;
    ushort_t* w2uhi = u2lo + HID * HID;                  // fused W2u pack
    ushort_t* w2ulo = w2uhi + HID * HID;
    float*    W2u   = (float*)(w2ulo + HID * HID);       // raw fused weight, 256 KB
    float*    bias2u = W2u + HID * HID;                  // fused bias, 1 KB
    float*    Pe   = bias2u + HID;                       // [B*NC,256] fp32, 16 MB
    ushort_t* Pn   = (ushort_t*)(Pe + (size_t)BSZ * NC * 256); // [B*NC,256] bf16, 8 MB

    // zero aggf + counts (contiguous at d_ws start)
    int n4 = (BSZ * NC * HID * 4 + BSZ * NC * 4) / 16;
    prep_kernel<<<PACK1B + FUSEB + 1 + ZEROB, 256, 0, stream>>>(
        mW1, uW1, uW2, mW2, ub1, mb2,
        w1hi, w1lo, u1hi, u1lo, u2hi, u2lo, W2u, bias2u, (float4*)d_ws, n4);
    hist_kernel<<<BSZ * NE / 256, 256, 0, stream>>>(eidx, counts);
    scan_kernel<<<BSZ + 32, 1024, 0, stream>>>(counts, woff, W2u, w2uhi, w2ulo);
    scatter_kernel<<<BSZ * NE / 256, 256, 0, stream>>>(eidx, woff, sorted);
    pre_kernel<<<BSZ * NC / 32, 512, 0, stream>>>(cell_x, w1hi, w1lo, u1hi, u1lo, Pe, Pn);
    edge_kernel<<<BSZ * NE / 64, 512, 0, stream>>>(Pe, eidx, sorted, eattr,
                                                   w1hi, w1lo, mb1, aggf);
    node_kernel<<<BSZ * NC / 32, 512, 0, stream>>>(cell_x, aggf, counts, Pn,
                                                   w2uhi, w2ulo, bias2u,
                                                   u2hi, u2lo, ub2,
                                                   gamma, beta, out);
}